// Round 12
// baseline (209.337 us; speedup 1.0000x reference)
//
#include <hip/hip_runtime.h>
#include <hip/hip_bf16.h>
#include <stdint.h>

// MultiHeadSelfAttention, B=1, S=4096, D_MODEL=768, H=12, Dk=64, causal.
// FP32 I/O, bf16 MFMA inside. Launches:
//   0) cvt_all    fp32->bf16
//   1) gemm_nt<1> QKV projections -> Q,K [H][S][64] bf16, V TRANSPOSED [H][64][S]
//        Q is pre-scaled by 0.125*log2(e) so flash softmax runs in exp2 domain.
//   2) flash_part causal flash attention, 32x32 S^T formulation, KV chunks 512
//   3) combine    merge chunk partials -> AO (exp2 domain)
//   4) gemm_nt<0> AO @ Wo^T -> d_out fp32
// R11: flash 32x32 MFMA + permlane32_swap (83.6->56.2us).
// R12: flash XCD swizzle kept (FETCH 58->14MB, 55.2us).
// R13-R15: flash single-buffer regressed; gemm 32x32 regressed; reverted.
// R16: gemm 64x128 retile + flash softmax despec: both NEUTRAL (187.3/187.5).
//      Non-flash ~132us invariant across SIX gemm variants -> gemms small or
//      overhead-bound; flash (55us) is the only directly-measurable target.
// R17 (this round): drop V LDS staging in flash (Common-mistake #7 / m169:
//      L2-resident data staged through LDS is pure overhead). PV B-operand
//      reads V^T directly from global (2 base addrs + 8 dwordx4/tile with
//      imm offsets). LDS 36.9->18.4 KB -> 8 blocks/CU capacity.

#define S_LEN  4096
#define DMODEL 768
#define NHEADS 12
#define LDSW   72          // padded LDS row stride (elems); 144B = 16B-aligned
#define WPH    144         // work items per head: 32+28+24+20+16+12+8+4
#define QSCALE 0.1803368801111437f   // 0.125 * log2(e)

typedef __attribute__((ext_vector_type(8))) __bf16 bf16x8;
typedef __attribute__((ext_vector_type(8))) unsigned short ushortx8;
typedef __attribute__((ext_vector_type(4))) unsigned short ushortx4;
typedef __attribute__((ext_vector_type(4))) unsigned int uintx4;
typedef __attribute__((ext_vector_type(2))) unsigned int uintx2;
typedef __attribute__((ext_vector_type(4))) float floatx4;
typedef __attribute__((ext_vector_type(16))) float floatx16;

__device__ __forceinline__ unsigned short f2bf(float f) {
    unsigned int u = __float_as_uint(f);
    u += 0x7fffu + ((u >> 16) & 1u);   // RNE
    return (unsigned short)(u >> 16);
}
__device__ __forceinline__ float bf2f(unsigned short v) {
    return __uint_as_float(((unsigned int)v) << 16);
}
// pack two f32 -> one dword of 2 bf16 (RNE); compiler fuses to v_cvt_pk_bf16_f32
__device__ __forceinline__ unsigned pack2bf(float lo, float hi) {
    const unsigned short ul = __builtin_bit_cast(unsigned short, (__bf16)lo);
    const unsigned short uh = __builtin_bit_cast(unsigned short, (__bf16)hi);
    return ((unsigned)uh << 16) | ul;
}

#if defined(__has_builtin)
#if __has_builtin(__builtin_amdgcn_exp2f)
#define EXP2(x) __builtin_amdgcn_exp2f(x)
#endif
#endif
#ifndef EXP2
#define EXP2(x) exp2f(x)
#endif

// v_permlane32_swap_b32: vdst[32:63] <-> vsrc[0:31].
__device__ __forceinline__ uintx2 plane32_swap(unsigned a, unsigned b) {
#if defined(__has_builtin) && __has_builtin(__builtin_amdgcn_permlane32_swap)
    auto r = __builtin_amdgcn_permlane32_swap(a, b, false, false);
    uintx2 out; out[0] = (unsigned)r[0]; out[1] = (unsigned)r[1];
    return out;
#else
    const int lane = (int)(threadIdx.x & 63);
    const unsigned as = (unsigned)__shfl_xor((int)a, 32, 64);
    const unsigned bs = (unsigned)__shfl_xor((int)b, 32, 64);
    uintx2 out;
    out[0] = (lane >= 32) ? bs : a;
    out[1] = (lane >= 32) ? b : as;
    return out;
#endif
}

// direct global->LDS copy, 16B/lane; lptr is the WAVE-UNIFORM base.
__device__ __forceinline__ void gl_lds16(const void* g, void* l) {
    __builtin_amdgcn_global_load_lds(
        (const __attribute__((address_space(1))) unsigned int*)g,
        (__attribute__((address_space(3))) unsigned int*)l,
        16, 0, 0);
}

// chunk offsets: chunk c covers qb in [4c, 32), count 32-4c
__device__ __constant__ int d_coff[9] = {0, 32, 60, 84, 104, 120, 132, 140, 144};

// ---------------- fused fp32->bf16 conversion ----------------
__global__ __launch_bounds__(256) void cvt_all(
    const float* __restrict__ x,  const float* __restrict__ Wq,
    const float* __restrict__ Wk, const float* __restrict__ Wv,
    const float* __restrict__ Wo,
    unsigned short* __restrict__ xb,  unsigned short* __restrict__ Wqb,
    unsigned short* __restrict__ Wkb, unsigned short* __restrict__ Wvb,
    unsigned short* __restrict__ Wob)
{
    int b = blockIdx.x;
    const float* src; unsigned short* dst;
    if (b < 1536)      { src = x;  dst = xb;  }
    else if (b < 1824) { src = Wq; dst = Wqb; b -= 1536; }
    else if (b < 2112) { src = Wk; dst = Wkb; b -= 1824; }
    else if (b < 2400) { src = Wv; dst = Wvb; b -= 2112; }
    else               { src = Wo; dst = Wob; b -= 2400; }
    const int i = (b * 256 + threadIdx.x) * 8;
    const float4 a0 = *(const float4*)(src + i);
    const float4 a1 = *(const float4*)(src + i + 4);
    ushortx8 o;
    o[0] = f2bf(a0.x); o[1] = f2bf(a0.y); o[2] = f2bf(a0.z); o[3] = f2bf(a0.w);
    o[4] = f2bf(a1.x); o[5] = f2bf(a1.y); o[6] = f2bf(a1.z); o[7] = f2bf(a1.w);
    *(ushortx8*)(dst + i) = o;
}

// ---------------- GEMM C = A * B^T, tile 64M x 128N ----------------
// MODE 0: fp32 out [M][N]. MODE 1: z=0 Q (scaled by QSCALE), z=1 K,
// head-major [H][M][64]; z=2 V TRANSPOSED: C2[(h*64+d)*M + m], b64 stores.
// 16x16x32 MFMA, 1-phase gl_lds staging (3 instrs/wave/step).
template <int MODE>
__global__ __launch_bounds__(256) void gemm_nt(
    const unsigned short* __restrict__ A,
    const unsigned short* __restrict__ B0,
    const unsigned short* __restrict__ B1,
    const unsigned short* __restrict__ B2,
    unsigned short* __restrict__ C0,
    unsigned short* __restrict__ C1,
    unsigned short* __restrict__ C2,
    float* __restrict__ Cf,
    int M, int N, int K)
{
    __shared__ __align__(16) unsigned short As[64 * 32];
    __shared__ __align__(16) unsigned short Bs[128 * 32];

    const int tid  = threadIdx.x;
    const int wave = tid >> 6;
    const int lane = tid & 63;
    const int quad = lane >> 4;
    const int l16  = lane & 15;
    const int wr   = wave >> 1;
    const int wc   = wave & 1;
    const int bm   = blockIdx.y * 64;
    const int bn   = blockIdx.x * 128;
    const int bz   = blockIdx.z;

    const unsigned short* B = B0;
    unsigned short* C = C0;
    if (MODE == 1) {
        if (bz == 1)      { B = B1; C = C1; }
        else if (bz == 2) { B = B2; C = C2; }
    }

    floatx4 acc[2][4];
    const floatx4 zf = {0.f, 0.f, 0.f, 0.f};
#pragma unroll
    for (int i = 0; i < 2; ++i)
#pragma unroll
        for (int j = 0; j < 4; ++j) acc[i][j] = zf;

    const int arow0 = wave * 16 + (lane >> 2);
    const int brow0 = wave * 32 + (lane >> 2);
    const int scol  = (lane & 3) * 8;

    for (int kb = 0; kb < K; kb += 32) {
        __syncthreads();
        {
            const unsigned short* ga = A + (size_t)(bm + arow0) * K + kb + scol;
            const unsigned short* gb = B + (size_t)(bn + brow0) * K + kb + scol;
            gl_lds16(ga, &As[wave * 512]);
            gl_lds16(gb, &Bs[wave * 1024]);
            gl_lds16(gb + (size_t)16 * K, &Bs[wave * 1024 + 512]);
        }
        __syncthreads();

        bf16x8 af[2], bfr[4];
#pragma unroll
        for (int i = 0; i < 2; ++i)
            af[i]  = *(const bf16x8*)&As[(wr * 32 + i * 16 + l16) * 32 + quad * 8];
#pragma unroll
        for (int j = 0; j < 4; ++j)
            bfr[j] = *(const bf16x8*)&Bs[(wc * 64 + j * 16 + l16) * 32 + quad * 8];
#pragma unroll
        for (int mi = 0; mi < 2; ++mi)
#pragma unroll
            for (int ni = 0; ni < 4; ++ni)
                acc[mi][ni] = __builtin_amdgcn_mfma_f32_16x16x32_bf16(af[mi], bfr[ni], acc[mi][ni], 0, 0, 0);
    }

    const float cscale = (MODE == 1 && bz == 0) ? QSCALE : 1.0f;

#pragma unroll
    for (int mi = 0; mi < 2; ++mi) {
#pragma unroll
        for (int ni = 0; ni < 4; ++ni) {
            const floatx4 v = acc[mi][ni];
            const int n = bn + wc * 64 + ni * 16 + l16;
            const int m0 = bm + wr * 32 + mi * 16 + quad * 4;
            if (MODE == 1 && bz == 2) {
                const int hh = n >> 6, d = n & 63;
                ushortx4 pv;
#pragma unroll
                for (int r = 0; r < 4; ++r) pv[r] = f2bf(v[r]);
                *(ushortx4*)&C[(size_t)(hh * 64 + d) * M + m0] = pv;
            } else {
#pragma unroll
                for (int r = 0; r < 4; ++r) {
                    const int m = m0 + r;
                    if (MODE == 0) {
                        Cf[(size_t)m * N + n] = v[r];
                    } else {
                        const int hh = n >> 6, d = n & 63;
                        C[((size_t)hh * M + m) * 64 + d] = f2bf(v[r] * cscale);
                    }
                }
            }
        }
    }
}

// ---------------- flash attention, 32x32 S^T formulation ----------------
// grid (WPH, NHEADS) + XCD swizzle, 256 thr = 4 waves, each wave 32 q.
// K double-buffered in LDS; V read DIRECTLY from global (L2-resident,
// Common-mistake #7/m169: staging L2-fit data through LDS is overhead).
// LDS 18.4 KB -> 8 blocks/CU capacity.
// sv C-layout (32x32x16): col q = lane&31, row kv = (r&3)+8*(r>>2)+4*(lane>>5).
__global__ __launch_bounds__(256, 4) void flash_part(
    const unsigned short* __restrict__ Qh,
    const unsigned short* __restrict__ Kh,
    const unsigned short* __restrict__ VhT,   // [H][64][S]
    unsigned short* __restrict__ AO,
    unsigned short* __restrict__ Opart,
    float* __restrict__ ml)
{
    __shared__ __align__(16) unsigned short Ks[2][64 * LDSW];   // [kv][d]

    const int tid  = threadIdx.x;
    const int wave = tid >> 6;
    const int lane = tid & 63;
    const int l31  = lane & 31;
    const int hi   = lane >> 5;     // 0/1
    const int hi8  = hi * 8;

    // XCD swizzle: blocks sharing a head's K/V land on one XCD's L2.
    int o = (int)blockIdx.y * WPH + blockIdx.x;      // nwg = 1728, %8 == 0
    o = (o & 7) * (1728 / 8) + (o >> 3);
    const int h = o / WPH;
    const int w = o % WPH;

    int c = 0;
#pragma unroll
    for (int j = 1; j < 8; ++j) c += (w >= d_coff[j]);
    const int qb = 4 * c + (w - d_coff[c]);

    const int q0       = qb * 128;
    const int kv_start = c * 512;
    const int kv_end   = min(kv_start + 512, q0 + 128);
    const int ntiles   = (kv_end - kv_start) >> 6;
    const int qbase    = q0 + wave * 32;

    const unsigned short* Qb  = Qh  + (size_t)h * S_LEN * 64;
    const unsigned short* Kb  = Kh  + (size_t)h * S_LEN * 64;
    const unsigned short* Vtb = VhT + (size_t)h * 64 * S_LEN;

    // Q B-frags: lane holds n=q=qbase+l31, k=d = dk*16 + hi8 + j
    bf16x8 qf[4];
#pragma unroll
    for (int dk = 0; dk < 4; ++dk)
        qf[dk] = *(const bf16x8*)&Qb[(size_t)(qbase + l31) * 64 + dk * 16 + hi8];

    // per-lane V^T row bases (rows l31 and 32+l31)
    const unsigned short* vrow0 = Vtb + (size_t)(l31)      * S_LEN;
    const unsigned short* vrow1 = Vtb + (size_t)(32 + l31) * S_LEN;

    float m_i = 0.f, l_i = 0.f;   // m starts at 0 (defer bound keeps p <= 2^11.54)
    floatx16 o0, o1;    // O cols d 0-31 / 32-63; rows q per C-layout
#pragma unroll
    for (int r = 0; r < 16; ++r) { o0[r] = 0.f; o1[r] = 0.f; }

    const int srow = tid >> 2;           // 0..63
    const int scol = (tid & 3) * 16;     // 0,16,32,48

    // prologue: stage K tile 0 into buf 0
    {
        const unsigned short* kp = Kb + (size_t)(kv_start + srow) * 64 + scol;
        const ushortx8 k0 = *(const ushortx8*)kp;
        const ushortx8 k1 = *(const ushortx8*)(kp + 8);
        *(ushortx8*)&Ks[0][srow * LDSW + scol]     = k0;
        *(ushortx8*)&Ks[0][srow * LDSW + scol + 8] = k1;
    }
    __syncthreads();

    for (int t = 0; t < ntiles; ++t) {
        const int buf = t & 1;
        const int kv0 = kv_start + t * 64;
        const bool pre = (t + 1 < ntiles);

        ushortx8 kr0, kr1;
        if (pre) {
            const unsigned short* kp = Kb + (size_t)(kv0 + 64 + srow) * 64 + scol;
            kr0 = *(const ushortx8*)kp;  kr1 = *(const ushortx8*)(kp + 8);
        }

        if (kv0 <= qbase + 31) {   // wave has unmasked work in this tile
            // S^T = K Q^T : two 32x32 outputs (kv rows 0-31 / 32-63)
            floatx16 sv0, sv1;
#pragma unroll
            for (int r = 0; r < 16; ++r) { sv0[r] = 0.f; sv1[r] = 0.f; }
            __builtin_amdgcn_s_setprio(1);
#pragma unroll
            for (int dk = 0; dk < 4; ++dk) {
                const bf16x8 kf0 = *(const bf16x8*)&Ks[buf][(l31)      * LDSW + dk * 16 + hi8];
                const bf16x8 kf1 = *(const bf16x8*)&Ks[buf][(32 + l31) * LDSW + dk * 16 + hi8];
                sv0 = __builtin_amdgcn_mfma_f32_32x32x16_bf16(kf0, qf[dk], sv0, 0, 0, 0);
                sv1 = __builtin_amdgcn_mfma_f32_32x32x16_bf16(kf1, qf[dk], sv1, 0, 0, 0);
            }
            __builtin_amdgcn_s_setprio(0);

            const int qcol = qbase + l31;
            if (kv0 + 63 > qbase) {     // causal mask needed
#pragma unroll
                for (int r = 0; r < 16; ++r) {
                    const int kvo = (r & 3) + 8 * (r >> 2) + 4 * hi;
                    if (kv0 + kvo > qcol)      sv0[r] = -1e9f;
                    if (kv0 + 32 + kvo > qcol) sv1[r] = -1e9f;
                }
            }

            const float m_old = m_i;
            float a_[8];
#pragma unroll
            for (int g = 0; g < 8; ++g)
                a_[g] = fmaxf(fmaxf(sv0[2*g], sv0[2*g+1]), fmaxf(sv1[2*g], sv1[2*g+1]));
            float mx = fmaxf(fmaxf(fmaxf(a_[0], a_[1]), fmaxf(a_[2], a_[3])),
                             fmaxf(fmaxf(a_[4], a_[5]), fmaxf(a_[6], a_[7])));
            // speculative exp2 vs m_old — overlaps the shfl chain
#pragma unroll
            for (int r = 0; r < 16; ++r) {
                sv0[r] = EXP2(sv0[r] - m_old);
                sv1[r] = EXP2(sv1[r] - m_old);
            }
            mx = fmaxf(mx, __shfl_xor(mx, 32, 64));
            const bool defer = (__all(mx <= m_old + 11.541560327f) != 0);
            float al = 1.f;
            if (!defer) {
                const float mn = fmaxf(m_old, mx);
                al = EXP2(m_old - mn);
                m_i = mn;
#pragma unroll
                for (int r = 0; r < 16; ++r) { sv0[r] *= al; sv1[r] *= al; }
            }
            // lane-partial row sum (merged once in epilogue)
            float s_[8];
#pragma unroll
            for (int g = 0; g < 8; ++g)
                s_[g] = (sv0[2*g] + sv0[2*g+1]) + (sv1[2*g] + sv1[2*g+1]);
            const float rs = ((s_[0] + s_[1]) + (s_[2] + s_[3])) + ((s_[4] + s_[5]) + (s_[6] + s_[7]));
            l_i = (defer ? l_i : l_i * al) + rs;

            // pack P pairs (kv 2g,2g+1) to bf16 RNE (v_cvt_pk-fusible)
            unsigned pk0[8], pk1[8];
#pragma unroll
            for (int g = 0; g < 8; ++g) {
                pk0[g] = pack2bf(sv0[2*g], sv0[2*g+1]);
                pk1[g] = pack2bf(sv1[2*g], sv1[2*g+1]);
            }

            if (!defer) {
#pragma unroll
                for (int r = 0; r < 16; ++r) {
                    const float a = __shfl(al, (r & 3) + 8 * (r >> 2) + 4 * hi, 64);
                    o0[r] *= a; o1[r] *= a;
                }
            }

            // O += P V: A-frag per kt via 2 permlane32_swap; B = V^T from
            // GLOBAL (L2-hit; lane-uniform col offsets fold into imm).
            const unsigned short* v0p = vrow0 + kv0;
            const unsigned short* v1p = vrow1 + kv0;
            __builtin_amdgcn_s_setprio(1);
#define PV_STEP(PK, KPAR, KT)                                                  \
            {                                                                  \
                uintx2 rA = plane32_swap(PK[(KPAR)*4 + 0], PK[(KPAR)*4 + 2]);  \
                uintx2 rB = plane32_swap(PK[(KPAR)*4 + 1], PK[(KPAR)*4 + 3]);  \
                uintx4 aw; aw[0] = rA[0]; aw[1] = rB[0]; aw[2] = rA[1]; aw[3] = rB[1]; \
                const bf16x8 paf = __builtin_bit_cast(bf16x8, aw);             \
                const int kvcol = (KT) * 16 + hi8;                             \
                const bf16x8 vf0 = *(const bf16x8*)(v0p + kvcol);              \
                const bf16x8 vf1 = *(const bf16x8*)(v1p + kvcol);              \
                o0 = __builtin_amdgcn_mfma_f32_32x32x16_bf16(paf, vf0, o0, 0, 0, 0);    \
                o1 = __builtin_amdgcn_mfma_f32_32x32x16_bf16(paf, vf1, o1, 0, 0, 0);    \
            }
            PV_STEP(pk0, 0, 0)
            PV_STEP(pk0, 1, 1)
            PV_STEP(pk1, 0, 2)
            PV_STEP(pk1, 1, 3)
#undef PV_STEP
            __builtin_amdgcn_s_setprio(0);
        }

        if (pre) {
            *(ushortx8*)&Ks[buf ^ 1][srow * LDSW + scol]     = kr0;
            *(ushortx8*)&Ks[buf ^ 1][srow * LDSW + scol + 8] = kr1;
        }
        __syncthreads();
    }

    // merge the lane-partial row sums (halves of kv live in lanes l, l+32)
    const float l_tot = l_i + __shfl_xor(l_i, 32, 64);

    // epilogue. O: col d = dblk*32 + l31, row q_local = (r&3)+8*(r>>2)+4*hi
    if (qb < 4) {
        const float invl = 1.0f / l_tot;
#pragma unroll
        for (int r = 0; r < 16; ++r) {
            const int ql = (r & 3) + 8 * (r >> 2) + 4 * hi;
            const float a = __shfl(invl, ql, 64);
            const int qr = qbase + ql;
            AO[(size_t)qr * DMODEL + h * 64 + l31]      = f2bf(o0[r] * a);
            AO[(size_t)qr * DMODEL + h * 64 + 32 + l31] = f2bf(o1[r] * a);
        }
    } else {
        const int slot = h * WPH + w;
        unsigned short* op = Opart + (size_t)slot * (128 * 64);
#pragma unroll
        for (int r = 0; r < 16; ++r) {
            const int ql = (r & 3) + 8 * (r >> 2) + 4 * hi;
            const int lr = wave * 32 + ql;
            op[lr * 64 + l31]      = f2bf(o0[r]);
            op[lr * 64 + 32 + l31] = f2bf(o1[r]);
        }
        if (hi == 0) {
            float* mlp = ml + (size_t)slot * 256;
            const int lr = wave * 32 + l31;
            mlp[lr * 2]     = m_i;
            mlp[lr * 2 + 1] = l_tot;
        }
    }
}

// ---------------- combine chunk partials (exp2 domain) ----------------
__global__ __launch_bounds__(256) void combine(
    const unsigned short* __restrict__ Opart,
    const float* __restrict__ ml,
    unsigned short* __restrict__ AO)
{
    const int qb  = 4 + blockIdx.x;          // qb in [4, 32)
    const int h   = blockIdx.y;
    const int row = threadIdx.x >> 1;
    const int ds  = (threadIdx.x & 1) * 32;
    const int nc  = (qb >> 2) + 1;           // chunks for this qb (2..8)

    int slots[8];
    for (int cI = 0; cI < 8; ++cI) slots[cI] = h * WPH + d_coff[cI] + (qb - 4 * cI);

    float mc[8], lc[8];
    float M = -3e38f;
    for (int cI = 0; cI < nc; ++cI) {
        mc[cI] = ml[(size_t)slots[cI] * 256 + row * 2];
        lc[cI] = ml[(size_t)slots[cI] * 256 + row * 2 + 1];
        M = fmaxf(M, mc[cI]);
    }
    float L = 0.f;
    float acc[32];
#pragma unroll
    for (int i = 0; i < 32; ++i) acc[i] = 0.f;

    for (int cI = 0; cI < nc; ++cI) {
        const float sc = EXP2(mc[cI] - M);
        L += sc * lc[cI];
        const unsigned short* op = Opart + (size_t)slots[cI] * (128 * 64) + row * 64 + ds;
#pragma unroll
        for (int g = 0; g < 4; ++g) {
            const ushortx8 a = *(const ushortx8*)(op + g * 8);
#pragma unroll
            for (int i = 0; i < 8; ++i) acc[g * 8 + i] += sc * bf2f(a[i]);
        }
    }
    const float inv = 1.0f / L;
    unsigned short* dst = AO + (size_t)(qb * 128 + row) * DMODEL + h * 64 + ds;
#pragma unroll
    for (int g = 0; g < 4; ++g) {
        ushortx8 ov;
#pragma unroll
        for (int i = 0; i < 8; ++i) ov[i] = f2bf(acc[g * 8 + i] * inv);
        *(ushortx8*)(dst + g * 8) = ov;
    }
}

extern "C" void kernel_launch(void* const* d_in, const int* in_sizes, int n_in,
                              void* d_out, int out_size, void* d_ws, size_t ws_size,
                              hipStream_t stream) {
    const float* x  = (const float*)d_in[0];
    const float* Wq = (const float*)d_in[1];
    const float* Wk = (const float*)d_in[2];
    const float* Wv = (const float*)d_in[3];
    const float* Wo = (const float*)d_in[4];

    const int xElems = S_LEN * DMODEL;
    const int wElems = DMODEL * DMODEL;
    const size_t headElems = (size_t)NHEADS * S_LEN * 64;
    const int nslots = NHEADS * WPH;   // 1728

    unsigned short* xb  = (unsigned short*)d_ws;
    unsigned short* Wqb = xb  + xElems;
    unsigned short* Wkb = Wqb + wElems;
    unsigned short* Wvb = Wkb + wElems;
    unsigned short* Wob = Wvb + wElems;
    unsigned short* Qh  = Wob + wElems;
    unsigned short* Kh  = Qh + headElems;
    unsigned short* Vt  = Kh + headElems;                    // [H][64][S]
    unsigned short* AO  = Vt + headElems;
    unsigned short* Opart = AO + xElems;                     // [1728][128*64]
    float* ml = (float*)(Opart + (size_t)nslots * 128 * 64); // [1728][256]

    cvt_all<<<dim3(2688), dim3(256), 0, stream>>>(x, Wq, Wk, Wv, Wo,
                                                  xb, Wqb, Wkb, Wvb, Wob);

    gemm_nt<1><<<dim3(DMODEL / 128, S_LEN / 64, 3), dim3(256), 0, stream>>>(
        xb, Wqb, Wkb, Wvb, Qh, Kh, Vt, nullptr, S_LEN, DMODEL, DMODEL);

    flash_part<<<dim3(WPH, NHEADS), dim3(256), 0, stream>>>(Qh, Kh, Vt, AO, Opart, ml);

    combine<<<dim3(28, NHEADS), dim3(256), 0, stream>>>(Opart, ml, AO);

    gemm_nt<0><<<dim3(DMODEL / 128, S_LEN / 64, 1), dim3(256), 0, stream>>>(
        AO, Wob, nullptr, nullptr, nullptr, nullptr, nullptr,
        (float*)d_out, S_LEN, DMODEL, DMODEL);
}

// Round 13
// 189.433 us; speedup vs baseline: 1.1051x; 1.1051x over previous
//
#include <hip/hip_runtime.h>
#include <hip/hip_bf16.h>
#include <stdint.h>

// MultiHeadSelfAttention, B=1, S=4096, D_MODEL=768, H=12, Dk=64, causal.
// FP32 I/O, bf16 MFMA inside. Launches:
//   0) cvt_all    fp32->bf16
//   1) gemm_nt<1> QKV projections -> Q,K [H][S][64] bf16, V TRANSPOSED [H][64][S]
//        Q is pre-scaled by 0.125*log2(e) so flash softmax runs in exp2 domain.
//   2) flash_part causal flash attention, 32x32 S^T formulation, KV chunks 512
//   3) combine    merge chunk partials -> AO (exp2 domain)
//   4) gemm_nt<0> AO @ Wo^T -> d_out fp32
// R11: flash 32x32 MFMA + permlane32_swap (83.6->56.2us).
// R12: flash XCD swizzle kept (FETCH 58->14MB, 55.2us).
// R13-R15: flash single-buffer regressed; gemm 32x32 regressed; reverted.
// R16: gemm 64x128 retile + flash softmax despec: neutral (187.5us best-tied).
// R17: V direct-from-global regressed 55->80us (64-way uncoalesced gather;
//      LDS staging existed to do that gather once, coalesced). REVERTED.
// R18 (this round): lock in measured-best configuration = R16 verbatim.

#define S_LEN  4096
#define DMODEL 768
#define NHEADS 12
#define LDSW   72          // padded LDS row stride (elems); 144B = 16B-aligned
#define WPH    144         // work items per head: 32+28+24+20+16+12+8+4
#define QSCALE 0.1803368801111437f   // 0.125 * log2(e)

typedef __attribute__((ext_vector_type(8))) __bf16 bf16x8;
typedef __attribute__((ext_vector_type(8))) unsigned short ushortx8;
typedef __attribute__((ext_vector_type(4))) unsigned short ushortx4;
typedef __attribute__((ext_vector_type(4))) unsigned int uintx4;
typedef __attribute__((ext_vector_type(2))) unsigned int uintx2;
typedef __attribute__((ext_vector_type(4))) float floatx4;
typedef __attribute__((ext_vector_type(16))) float floatx16;

__device__ __forceinline__ unsigned short f2bf(float f) {
    unsigned int u = __float_as_uint(f);
    u += 0x7fffu + ((u >> 16) & 1u);   // RNE
    return (unsigned short)(u >> 16);
}
__device__ __forceinline__ float bf2f(unsigned short v) {
    return __uint_as_float(((unsigned int)v) << 16);
}
// pack two f32 -> one dword of 2 bf16 (RNE); compiler fuses to v_cvt_pk_bf16_f32
__device__ __forceinline__ unsigned pack2bf(float lo, float hi) {
    const unsigned short ul = __builtin_bit_cast(unsigned short, (__bf16)lo);
    const unsigned short uh = __builtin_bit_cast(unsigned short, (__bf16)hi);
    return ((unsigned)uh << 16) | ul;
}

#if defined(__has_builtin)
#if __has_builtin(__builtin_amdgcn_exp2f)
#define EXP2(x) __builtin_amdgcn_exp2f(x)
#endif
#endif
#ifndef EXP2
#define EXP2(x) exp2f(x)
#endif

// v_permlane32_swap_b32: vdst[32:63] <-> vsrc[0:31].
__device__ __forceinline__ uintx2 plane32_swap(unsigned a, unsigned b) {
#if defined(__has_builtin) && __has_builtin(__builtin_amdgcn_permlane32_swap)
    auto r = __builtin_amdgcn_permlane32_swap(a, b, false, false);
    uintx2 out; out[0] = (unsigned)r[0]; out[1] = (unsigned)r[1];
    return out;
#else
    const int lane = (int)(threadIdx.x & 63);
    const unsigned as = (unsigned)__shfl_xor((int)a, 32, 64);
    const unsigned bs = (unsigned)__shfl_xor((int)b, 32, 64);
    uintx2 out;
    out[0] = (lane >= 32) ? bs : a;
    out[1] = (lane >= 32) ? b : as;
    return out;
#endif
}

// direct global->LDS copy, 16B/lane; lptr is the WAVE-UNIFORM base.
__device__ __forceinline__ void gl_lds16(const void* g, void* l) {
    __builtin_amdgcn_global_load_lds(
        (const __attribute__((address_space(1))) unsigned int*)g,
        (__attribute__((address_space(3))) unsigned int*)l,
        16, 0, 0);
}

// chunk offsets: chunk c covers qb in [4c, 32), count 32-4c
__device__ __constant__ int d_coff[9] = {0, 32, 60, 84, 104, 120, 132, 140, 144};

// ---------------- fused fp32->bf16 conversion ----------------
__global__ __launch_bounds__(256) void cvt_all(
    const float* __restrict__ x,  const float* __restrict__ Wq,
    const float* __restrict__ Wk, const float* __restrict__ Wv,
    const float* __restrict__ Wo,
    unsigned short* __restrict__ xb,  unsigned short* __restrict__ Wqb,
    unsigned short* __restrict__ Wkb, unsigned short* __restrict__ Wvb,
    unsigned short* __restrict__ Wob)
{
    int b = blockIdx.x;
    const float* src; unsigned short* dst;
    if (b < 1536)      { src = x;  dst = xb;  }
    else if (b < 1824) { src = Wq; dst = Wqb; b -= 1536; }
    else if (b < 2112) { src = Wk; dst = Wkb; b -= 1824; }
    else if (b < 2400) { src = Wv; dst = Wvb; b -= 2112; }
    else               { src = Wo; dst = Wob; b -= 2400; }
    const int i = (b * 256 + threadIdx.x) * 8;
    const float4 a0 = *(const float4*)(src + i);
    const float4 a1 = *(const float4*)(src + i + 4);
    ushortx8 o;
    o[0] = f2bf(a0.x); o[1] = f2bf(a0.y); o[2] = f2bf(a0.z); o[3] = f2bf(a0.w);
    o[4] = f2bf(a1.x); o[5] = f2bf(a1.y); o[6] = f2bf(a1.z); o[7] = f2bf(a1.w);
    *(ushortx8*)(dst + i) = o;
}

// ---------------- GEMM C = A * B^T, tile 64M x 128N ----------------
// MODE 0: fp32 out [M][N]. MODE 1: z=0 Q (scaled by QSCALE), z=1 K,
// head-major [H][M][64]; z=2 V TRANSPOSED: C2[(h*64+d)*M + m], b64 stores.
// 16x16x32 MFMA, 1-phase gl_lds staging (3 instrs/wave/step).
template <int MODE>
__global__ __launch_bounds__(256) void gemm_nt(
    const unsigned short* __restrict__ A,
    const unsigned short* __restrict__ B0,
    const unsigned short* __restrict__ B1,
    const unsigned short* __restrict__ B2,
    unsigned short* __restrict__ C0,
    unsigned short* __restrict__ C1,
    unsigned short* __restrict__ C2,
    float* __restrict__ Cf,
    int M, int N, int K)
{
    __shared__ __align__(16) unsigned short As[64 * 32];
    __shared__ __align__(16) unsigned short Bs[128 * 32];

    const int tid  = threadIdx.x;
    const int wave = tid >> 6;
    const int lane = tid & 63;
    const int quad = lane >> 4;
    const int l16  = lane & 15;
    const int wr   = wave >> 1;
    const int wc   = wave & 1;
    const int bm   = blockIdx.y * 64;
    const int bn   = blockIdx.x * 128;
    const int bz   = blockIdx.z;

    const unsigned short* B = B0;
    unsigned short* C = C0;
    if (MODE == 1) {
        if (bz == 1)      { B = B1; C = C1; }
        else if (bz == 2) { B = B2; C = C2; }
    }

    floatx4 acc[2][4];
    const floatx4 zf = {0.f, 0.f, 0.f, 0.f};
#pragma unroll
    for (int i = 0; i < 2; ++i)
#pragma unroll
        for (int j = 0; j < 4; ++j) acc[i][j] = zf;

    const int arow0 = wave * 16 + (lane >> 2);
    const int brow0 = wave * 32 + (lane >> 2);
    const int scol  = (lane & 3) * 8;

    for (int kb = 0; kb < K; kb += 32) {
        __syncthreads();
        {
            const unsigned short* ga = A + (size_t)(bm + arow0) * K + kb + scol;
            const unsigned short* gb = B + (size_t)(bn + brow0) * K + kb + scol;
            gl_lds16(ga, &As[wave * 512]);
            gl_lds16(gb, &Bs[wave * 1024]);
            gl_lds16(gb + (size_t)16 * K, &Bs[wave * 1024 + 512]);
        }
        __syncthreads();

        bf16x8 af[2], bfr[4];
#pragma unroll
        for (int i = 0; i < 2; ++i)
            af[i]  = *(const bf16x8*)&As[(wr * 32 + i * 16 + l16) * 32 + quad * 8];
#pragma unroll
        for (int j = 0; j < 4; ++j)
            bfr[j] = *(const bf16x8*)&Bs[(wc * 64 + j * 16 + l16) * 32 + quad * 8];
#pragma unroll
        for (int mi = 0; mi < 2; ++mi)
#pragma unroll
            for (int ni = 0; ni < 4; ++ni)
                acc[mi][ni] = __builtin_amdgcn_mfma_f32_16x16x32_bf16(af[mi], bfr[ni], acc[mi][ni], 0, 0, 0);
    }

    const float cscale = (MODE == 1 && bz == 0) ? QSCALE : 1.0f;

#pragma unroll
    for (int mi = 0; mi < 2; ++mi) {
#pragma unroll
        for (int ni = 0; ni < 4; ++ni) {
            const floatx4 v = acc[mi][ni];
            const int n = bn + wc * 64 + ni * 16 + l16;
            const int m0 = bm + wr * 32 + mi * 16 + quad * 4;
            if (MODE == 1 && bz == 2) {
                const int hh = n >> 6, d = n & 63;
                ushortx4 pv;
#pragma unroll
                for (int r = 0; r < 4; ++r) pv[r] = f2bf(v[r]);
                *(ushortx4*)&C[(size_t)(hh * 64 + d) * M + m0] = pv;
            } else {
#pragma unroll
                for (int r = 0; r < 4; ++r) {
                    const int m = m0 + r;
                    if (MODE == 0) {
                        Cf[(size_t)m * N + n] = v[r];
                    } else {
                        const int hh = n >> 6, d = n & 63;
                        C[((size_t)hh * M + m) * 64 + d] = f2bf(v[r] * cscale);
                    }
                }
            }
        }
    }
}

// ---------------- flash attention, 32x32 S^T formulation ----------------
// grid (WPH, NHEADS) + XCD swizzle, 256 thr = 4 waves, each wave 32 q.
// DOUBLE-buffered LDS, one barrier per tile (R12-proven).
// m_i init 0; speculative exp2 vs m_old; l_i lane-partial, merged in epilogue.
// sv C-layout (32x32x16): col q = lane&31, row kv = (r&3)+8*(r>>2)+4*(lane>>5).
__global__ __launch_bounds__(256, 4) void flash_part(
    const unsigned short* __restrict__ Qh,
    const unsigned short* __restrict__ Kh,
    const unsigned short* __restrict__ VhT,   // [H][64][S]
    unsigned short* __restrict__ AO,
    unsigned short* __restrict__ Opart,
    float* __restrict__ ml)
{
    __shared__ __align__(16) unsigned short Ks[2][64 * LDSW];   // [kv][d]
    __shared__ __align__(16) unsigned short Vs[2][64 * LDSW];   // [d][kv]

    const int tid  = threadIdx.x;
    const int wave = tid >> 6;
    const int lane = tid & 63;
    const int l31  = lane & 31;
    const int hi   = lane >> 5;     // 0/1
    const int hi8  = hi * 8;

    // XCD swizzle: blocks sharing a head's K/V land on one XCD's L2.
    int o = (int)blockIdx.y * WPH + blockIdx.x;      // nwg = 1728, %8 == 0
    o = (o & 7) * (1728 / 8) + (o >> 3);
    const int h = o / WPH;
    const int w = o % WPH;

    int c = 0;
#pragma unroll
    for (int j = 1; j < 8; ++j) c += (w >= d_coff[j]);
    const int qb = 4 * c + (w - d_coff[c]);

    const int q0       = qb * 128;
    const int kv_start = c * 512;
    const int kv_end   = min(kv_start + 512, q0 + 128);
    const int ntiles   = (kv_end - kv_start) >> 6;
    const int qbase    = q0 + wave * 32;

    const unsigned short* Qb  = Qh  + (size_t)h * S_LEN * 64;
    const unsigned short* Kb  = Kh  + (size_t)h * S_LEN * 64;
    const unsigned short* Vtb = VhT + (size_t)h * 64 * S_LEN;

    // Q B-frags: lane holds n=q=qbase+l31, k=d = dk*16 + hi8 + j
    bf16x8 qf[4];
#pragma unroll
    for (int dk = 0; dk < 4; ++dk)
        qf[dk] = *(const bf16x8*)&Qb[(size_t)(qbase + l31) * 64 + dk * 16 + hi8];

    float m_i = 0.f, l_i = 0.f;   // m starts at 0 (defer bound keeps p <= 2^11.54)
    floatx16 o0, o1;    // O cols d 0-31 / 32-63; rows q per C-layout
#pragma unroll
    for (int r = 0; r < 16; ++r) { o0[r] = 0.f; o1[r] = 0.f; }

    const int srow = tid >> 2;           // 0..63
    const int scol = (tid & 3) * 16;     // 0,16,32,48

    // prologue: stage tile 0 into buf 0
    {
        const unsigned short* kp = Kb + (size_t)(kv_start + srow) * 64 + scol;
        const unsigned short* vp = Vtb + (size_t)srow * S_LEN + kv_start + scol;
        const ushortx8 k0 = *(const ushortx8*)kp;
        const ushortx8 k1 = *(const ushortx8*)(kp + 8);
        const ushortx8 v0 = *(const ushortx8*)vp;
        const ushortx8 v1 = *(const ushortx8*)(vp + 8);
        *(ushortx8*)&Ks[0][srow * LDSW + scol]     = k0;
        *(ushortx8*)&Ks[0][srow * LDSW + scol + 8] = k1;
        *(ushortx8*)&Vs[0][srow * LDSW + scol]     = v0;
        *(ushortx8*)&Vs[0][srow * LDSW + scol + 8] = v1;
    }
    __syncthreads();

    for (int t = 0; t < ntiles; ++t) {
        const int buf = t & 1;
        const int kv0 = kv_start + t * 64;
        const bool pre = (t + 1 < ntiles);

        ushortx8 kr0, kr1, vr0, vr1;
        if (pre) {
            const unsigned short* kp = Kb + (size_t)(kv0 + 64 + srow) * 64 + scol;
            const unsigned short* vp = Vtb + (size_t)srow * S_LEN + kv0 + 64 + scol;
            kr0 = *(const ushortx8*)kp;  kr1 = *(const ushortx8*)(kp + 8);
            vr0 = *(const ushortx8*)vp;  vr1 = *(const ushortx8*)(vp + 8);
        }

        if (kv0 <= qbase + 31) {   // wave has unmasked work in this tile
            // S^T = K Q^T : two 32x32 outputs (kv rows 0-31 / 32-63)
            floatx16 sv0, sv1;
#pragma unroll
            for (int r = 0; r < 16; ++r) { sv0[r] = 0.f; sv1[r] = 0.f; }
            __builtin_amdgcn_s_setprio(1);
#pragma unroll
            for (int dk = 0; dk < 4; ++dk) {
                const bf16x8 kf0 = *(const bf16x8*)&Ks[buf][(l31)      * LDSW + dk * 16 + hi8];
                const bf16x8 kf1 = *(const bf16x8*)&Ks[buf][(32 + l31) * LDSW + dk * 16 + hi8];
                sv0 = __builtin_amdgcn_mfma_f32_32x32x16_bf16(kf0, qf[dk], sv0, 0, 0, 0);
                sv1 = __builtin_amdgcn_mfma_f32_32x32x16_bf16(kf1, qf[dk], sv1, 0, 0, 0);
            }
            __builtin_amdgcn_s_setprio(0);

            const int qcol = qbase + l31;
            if (kv0 + 63 > qbase) {     // causal mask needed
#pragma unroll
                for (int r = 0; r < 16; ++r) {
                    const int kvo = (r & 3) + 8 * (r >> 2) + 4 * hi;
                    if (kv0 + kvo > qcol)      sv0[r] = -1e9f;
                    if (kv0 + 32 + kvo > qcol) sv1[r] = -1e9f;
                }
            }

            const float m_old = m_i;
            // local max tree (reads sv BEFORE the destructive exp2)
            float a_[8];
#pragma unroll
            for (int g = 0; g < 8; ++g)
                a_[g] = fmaxf(fmaxf(sv0[2*g], sv0[2*g+1]), fmaxf(sv1[2*g], sv1[2*g+1]));
            float mx = fmaxf(fmaxf(fmaxf(a_[0], a_[1]), fmaxf(a_[2], a_[3])),
                             fmaxf(fmaxf(a_[4], a_[5]), fmaxf(a_[6], a_[7])));
            // speculative exp2 vs m_old — issues now, overlaps the shfl chain
#pragma unroll
            for (int r = 0; r < 16; ++r) {
                sv0[r] = EXP2(sv0[r] - m_old);
                sv1[r] = EXP2(sv1[r] - m_old);
            }
            mx = fmaxf(mx, __shfl_xor(mx, 32, 64));
            const bool defer = (__all(mx <= m_old + 11.541560327f) != 0);
            float al = 1.f;
            if (!defer) {
                const float mn = fmaxf(m_old, mx);
                al = EXP2(m_old - mn);
                m_i = mn;
#pragma unroll
                for (int r = 0; r < 16; ++r) { sv0[r] *= al; sv1[r] *= al; }
            }
            // lane-partial row sum (NO per-tile shfl; merged in epilogue)
            float s_[8];
#pragma unroll
            for (int g = 0; g < 8; ++g)
                s_[g] = (sv0[2*g] + sv0[2*g+1]) + (sv1[2*g] + sv1[2*g+1]);
            const float rs = ((s_[0] + s_[1]) + (s_[2] + s_[3])) + ((s_[4] + s_[5]) + (s_[6] + s_[7]));
            l_i = (defer ? l_i : l_i * al) + rs;

            // pack P pairs (kv 2g,2g+1) to bf16 RNE (v_cvt_pk-fusible)
            unsigned pk0[8], pk1[8];
#pragma unroll
            for (int g = 0; g < 8; ++g) {
                pk0[g] = pack2bf(sv0[2*g], sv0[2*g+1]);
                pk1[g] = pack2bf(sv1[2*g], sv1[2*g+1]);
            }

            if (!defer) {
                // rescale O rows; row q_local = (r&3)+8*(r>>2)+4*hi
#pragma unroll
                for (int r = 0; r < 16; ++r) {
                    const float a = __shfl(al, (r & 3) + 8 * (r >> 2) + 4 * hi, 64);
                    o0[r] *= a; o1[r] *= a;
                }
            }

            // O += P V: A-frag per kt (kv 16-block) via 2 permlane32_swap.
            __builtin_amdgcn_s_setprio(1);
#define PV_STEP(PK, KPAR, KT)                                                  \
            {                                                                  \
                uintx2 rA = plane32_swap(PK[(KPAR)*4 + 0], PK[(KPAR)*4 + 2]);  \
                uintx2 rB = plane32_swap(PK[(KPAR)*4 + 1], PK[(KPAR)*4 + 3]);  \
                uintx4 aw; aw[0] = rA[0]; aw[1] = rB[0]; aw[2] = rA[1]; aw[3] = rB[1]; \
                const bf16x8 paf = __builtin_bit_cast(bf16x8, aw);             \
                const int kvcol = (KT) * 16 + hi8;                             \
                const bf16x8 vf0 = *(const bf16x8*)&Vs[buf][(l31)      * LDSW + kvcol]; \
                const bf16x8 vf1 = *(const bf16x8*)&Vs[buf][(32 + l31) * LDSW + kvcol]; \
                o0 = __builtin_amdgcn_mfma_f32_32x32x16_bf16(paf, vf0, o0, 0, 0, 0);    \
                o1 = __builtin_amdgcn_mfma_f32_32x32x16_bf16(paf, vf1, o1, 0, 0, 0);    \
            }
            PV_STEP(pk0, 0, 0)
            PV_STEP(pk0, 1, 1)
            PV_STEP(pk1, 0, 2)
            PV_STEP(pk1, 1, 3)
#undef PV_STEP
            __builtin_amdgcn_s_setprio(0);
        }

        if (pre) {
            *(ushortx8*)&Ks[buf ^ 1][srow * LDSW + scol]     = kr0;
            *(ushortx8*)&Ks[buf ^ 1][srow * LDSW + scol + 8] = kr1;
            *(ushortx8*)&Vs[buf ^ 1][srow * LDSW + scol]     = vr0;
            *(ushortx8*)&Vs[buf ^ 1][srow * LDSW + scol + 8] = vr1;
        }
        __syncthreads();
    }

    // merge the lane-partial row sums (halves of kv live in lanes l, l+32)
    const float l_tot = l_i + __shfl_xor(l_i, 32, 64);

    // epilogue. O: col d = dblk*32 + l31, row q_local = (r&3)+8*(r>>2)+4*hi
    if (qb < 4) {
        const float invl = 1.0f / l_tot;
#pragma unroll
        for (int r = 0; r < 16; ++r) {
            const int ql = (r & 3) + 8 * (r >> 2) + 4 * hi;
            const float a = __shfl(invl, ql, 64);
            const int qr = qbase + ql;
            AO[(size_t)qr * DMODEL + h * 64 + l31]      = f2bf(o0[r] * a);
            AO[(size_t)qr * DMODEL + h * 64 + 32 + l31] = f2bf(o1[r] * a);
        }
    } else {
        const int slot = h * WPH + w;
        unsigned short* op = Opart + (size_t)slot * (128 * 64);
#pragma unroll
        for (int r = 0; r < 16; ++r) {
            const int ql = (r & 3) + 8 * (r >> 2) + 4 * hi;
            const int lr = wave * 32 + ql;
            op[lr * 64 + l31]      = f2bf(o0[r]);
            op[lr * 64 + 32 + l31] = f2bf(o1[r]);
        }
        if (hi == 0) {
            float* mlp = ml + (size_t)slot * 256;
            const int lr = wave * 32 + l31;
            mlp[lr * 2]     = m_i;
            mlp[lr * 2 + 1] = l_tot;
        }
    }
}

// ---------------- combine chunk partials (exp2 domain) ----------------
__global__ __launch_bounds__(256) void combine(
    const unsigned short* __restrict__ Opart,
    const float* __restrict__ ml,
    unsigned short* __restrict__ AO)
{
    const int qb  = 4 + blockIdx.x;          // qb in [4, 32)
    const int h   = blockIdx.y;
    const int row = threadIdx.x >> 1;
    const int ds  = (threadIdx.x & 1) * 32;
    const int nc  = (qb >> 2) + 1;           // chunks for this qb (2..8)

    int slots[8];
    for (int cI = 0; cI < 8; ++cI) slots[cI] = h * WPH + d_coff[cI] + (qb - 4 * cI);

    float mc[8], lc[8];
    float M = -3e38f;
    for (int cI = 0; cI < nc; ++cI) {
        mc[cI] = ml[(size_t)slots[cI] * 256 + row * 2];
        lc[cI] = ml[(size_t)slots[cI] * 256 + row * 2 + 1];
        M = fmaxf(M, mc[cI]);
    }
    float L = 0.f;
    float acc[32];
#pragma unroll
    for (int i = 0; i < 32; ++i) acc[i] = 0.f;

    for (int cI = 0; cI < nc; ++cI) {
        const float sc = EXP2(mc[cI] - M);
        L += sc * lc[cI];
        const unsigned short* op = Opart + (size_t)slots[cI] * (128 * 64) + row * 64 + ds;
#pragma unroll
        for (int g = 0; g < 4; ++g) {
            const ushortx8 a = *(const ushortx8*)(op + g * 8);
#pragma unroll
            for (int i = 0; i < 8; ++i) acc[g * 8 + i] += sc * bf2f(a[i]);
        }
    }
    const float inv = 1.0f / L;
    unsigned short* dst = AO + (size_t)(qb * 128 + row) * DMODEL + h * 64 + ds;
#pragma unroll
    for (int g = 0; g < 4; ++g) {
        ushortx8 ov;
#pragma unroll
        for (int i = 0; i < 8; ++i) ov[i] = f2bf(acc[g * 8 + i] * inv);
        *(ushortx8*)(dst + g * 8) = ov;
    }
}

extern "C" void kernel_launch(void* const* d_in, const int* in_sizes, int n_in,
                              void* d_out, int out_size, void* d_ws, size_t ws_size,
                              hipStream_t stream) {
    const float* x  = (const float*)d_in[0];
    const float* Wq = (const float*)d_in[1];
    const float* Wk = (const float*)d_in[2];
    const float* Wv = (const float*)d_in[3];
    const float* Wo = (const float*)d_in[4];

    const int xElems = S_LEN * DMODEL;
    const int wElems = DMODEL * DMODEL;
    const size_t headElems = (size_t)NHEADS * S_LEN * 64;
    const int nslots = NHEADS * WPH;   // 1728

    unsigned short* xb  = (unsigned short*)d_ws;
    unsigned short* Wqb = xb  + xElems;
    unsigned short* Wkb = Wqb + wElems;
    unsigned short* Wvb = Wkb + wElems;
    unsigned short* Wob = Wvb + wElems;
    unsigned short* Qh  = Wob + wElems;
    unsigned short* Kh  = Qh + headElems;
    unsigned short* Vt  = Kh + headElems;                    // [H][64][S]
    unsigned short* AO  = Vt + headElems;
    unsigned short* Opart = AO + xElems;                     // [1728][128*64]
    float* ml = (float*)(Opart + (size_t)nslots * 128 * 64); // [1728][256]

    cvt_all<<<dim3(2688), dim3(256), 0, stream>>>(x, Wq, Wk, Wv, Wo,
                                                  xb, Wqb, Wkb, Wvb, Wob);

    gemm_nt<1><<<dim3(DMODEL / 128, S_LEN / 64, 3), dim3(256), 0, stream>>>(
        xb, Wqb, Wkb, Wvb, Qh, Kh, Vt, nullptr, S_LEN, DMODEL, DMODEL);

    flash_part<<<dim3(WPH, NHEADS), dim3(256), 0, stream>>>(Qh, Kh, Vt, AO, Opart, ml);

    combine<<<dim3(28, NHEADS), dim3(256), 0, stream>>>(Opart, ml, AO);

    gemm_nt<0><<<dim3(DMODEL / 128, S_LEN / 64, 1), dim3(256), 0, stream>>>(
        AO, Wob, nullptr, nullptr, nullptr, nullptr, nullptr,
        (float*)d_out, S_LEN, DMODEL, DMODEL);
}

// Round 14
// 187.211 us; speedup vs baseline: 1.1182x; 1.0119x over previous
//
#include <hip/hip_runtime.h>
#include <hip/hip_bf16.h>
#include <stdint.h>

// MultiHeadSelfAttention, B=1, S=4096, D_MODEL=768, H=12, Dk=64, causal.
// FP32 I/O, bf16 MFMA inside. Launches:
//   0) cvt_all    fp32->bf16
//   1) gemm_nt<1> QKV projections -> Q,K [H][S][64] bf16, V TRANSPOSED [H][64][S]
//        Q is pre-scaled by 0.125*log2(e) so flash softmax runs in exp2 domain.
//   2) flash_part causal flash attention, 32x32 S^T formulation, KV chunks 512
//   3) combine    merge chunk partials -> AO (exp2 domain)
//   4) gemm_nt<0> AO @ Wo^T -> d_out fp32
// R11: flash 32x32 MFMA + permlane32_swap (83.6->56.2us).
// R12: flash XCD swizzle kept; gemm 32x32+dbuf+swizzle bundle +6us.
// R14: isolated gemm 32x32 1-phase also +6us -> the +6 was the 32x32
//      16-way LDS conflict, NOT the dbuf. dbuf never isolated.
// R15-R18: plateau 187.3-189.4us; flash 55-58, non-flash ~131 invariant.
// R17: V direct-from-global regressed (uncoalesced gather). REVERTED.
// R19 (this round): gemm 2-phase DOUBLE-BUFFER, isolated — 16x16 MFMA,
//      64x128 tile, no swizzle. Issue next STAGE before compute; one
//      barrier/K-step; global-load latency hides under MFMA (T3 minimum
//      2-phase). LDS 12->24KB (still >=5 blocks/CU). Flash unchanged.

#define S_LEN  4096
#define DMODEL 768
#define NHEADS 12
#define LDSW   72          // padded LDS row stride (elems); 144B = 16B-aligned
#define WPH    144         // work items per head: 32+28+24+20+16+12+8+4
#define QSCALE 0.1803368801111437f   // 0.125 * log2(e)

typedef __attribute__((ext_vector_type(8))) __bf16 bf16x8;
typedef __attribute__((ext_vector_type(8))) unsigned short ushortx8;
typedef __attribute__((ext_vector_type(4))) unsigned short ushortx4;
typedef __attribute__((ext_vector_type(4))) unsigned int uintx4;
typedef __attribute__((ext_vector_type(2))) unsigned int uintx2;
typedef __attribute__((ext_vector_type(4))) float floatx4;
typedef __attribute__((ext_vector_type(16))) float floatx16;

__device__ __forceinline__ unsigned short f2bf(float f) {
    unsigned int u = __float_as_uint(f);
    u += 0x7fffu + ((u >> 16) & 1u);   // RNE
    return (unsigned short)(u >> 16);
}
__device__ __forceinline__ float bf2f(unsigned short v) {
    return __uint_as_float(((unsigned int)v) << 16);
}
// pack two f32 -> one dword of 2 bf16 (RNE); compiler fuses to v_cvt_pk_bf16_f32
__device__ __forceinline__ unsigned pack2bf(float lo, float hi) {
    const unsigned short ul = __builtin_bit_cast(unsigned short, (__bf16)lo);
    const unsigned short uh = __builtin_bit_cast(unsigned short, (__bf16)hi);
    return ((unsigned)uh << 16) | ul;
}

#if defined(__has_builtin)
#if __has_builtin(__builtin_amdgcn_exp2f)
#define EXP2(x) __builtin_amdgcn_exp2f(x)
#endif
#endif
#ifndef EXP2
#define EXP2(x) exp2f(x)
#endif

// v_permlane32_swap_b32: vdst[32:63] <-> vsrc[0:31].
__device__ __forceinline__ uintx2 plane32_swap(unsigned a, unsigned b) {
#if defined(__has_builtin) && __has_builtin(__builtin_amdgcn_permlane32_swap)
    auto r = __builtin_amdgcn_permlane32_swap(a, b, false, false);
    uintx2 out; out[0] = (unsigned)r[0]; out[1] = (unsigned)r[1];
    return out;
#else
    const int lane = (int)(threadIdx.x & 63);
    const unsigned as = (unsigned)__shfl_xor((int)a, 32, 64);
    const unsigned bs = (unsigned)__shfl_xor((int)b, 32, 64);
    uintx2 out;
    out[0] = (lane >= 32) ? bs : a;
    out[1] = (lane >= 32) ? b : as;
    return out;
#endif
}

// direct global->LDS copy, 16B/lane; lptr is the WAVE-UNIFORM base.
__device__ __forceinline__ void gl_lds16(const void* g, void* l) {
    __builtin_amdgcn_global_load_lds(
        (const __attribute__((address_space(1))) unsigned int*)g,
        (__attribute__((address_space(3))) unsigned int*)l,
        16, 0, 0);
}

// chunk offsets: chunk c covers qb in [4c, 32), count 32-4c
__device__ __constant__ int d_coff[9] = {0, 32, 60, 84, 104, 120, 132, 140, 144};

// ---------------- fused fp32->bf16 conversion ----------------
__global__ __launch_bounds__(256) void cvt_all(
    const float* __restrict__ x,  const float* __restrict__ Wq,
    const float* __restrict__ Wk, const float* __restrict__ Wv,
    const float* __restrict__ Wo,
    unsigned short* __restrict__ xb,  unsigned short* __restrict__ Wqb,
    unsigned short* __restrict__ Wkb, unsigned short* __restrict__ Wvb,
    unsigned short* __restrict__ Wob)
{
    int b = blockIdx.x;
    const float* src; unsigned short* dst;
    if (b < 1536)      { src = x;  dst = xb;  }
    else if (b < 1824) { src = Wq; dst = Wqb; b -= 1536; }
    else if (b < 2112) { src = Wk; dst = Wkb; b -= 1824; }
    else if (b < 2400) { src = Wv; dst = Wvb; b -= 2112; }
    else               { src = Wo; dst = Wob; b -= 2400; }
    const int i = (b * 256 + threadIdx.x) * 8;
    const float4 a0 = *(const float4*)(src + i);
    const float4 a1 = *(const float4*)(src + i + 4);
    ushortx8 o;
    o[0] = f2bf(a0.x); o[1] = f2bf(a0.y); o[2] = f2bf(a0.z); o[3] = f2bf(a0.w);
    o[4] = f2bf(a1.x); o[5] = f2bf(a1.y); o[6] = f2bf(a1.z); o[7] = f2bf(a1.w);
    *(ushortx8*)(dst + i) = o;
}

// ---------------- GEMM C = A * B^T, tile 64M x 128N ----------------
// MODE 0: fp32 out [M][N]. MODE 1: z=0 Q (scaled by QSCALE), z=1 K,
// head-major [H][M][64]; z=2 V TRANSPOSED: C2[(h*64+d)*M + m], b64 stores.
// 16x16x32 MFMA, 2-phase DOUBLE-BUFFERED gl_lds staging: next K-step's
// loads issue before compute; one barrier per step.
template <int MODE>
__global__ __launch_bounds__(256) void gemm_nt(
    const unsigned short* __restrict__ A,
    const unsigned short* __restrict__ B0,
    const unsigned short* __restrict__ B1,
    const unsigned short* __restrict__ B2,
    unsigned short* __restrict__ C0,
    unsigned short* __restrict__ C1,
    unsigned short* __restrict__ C2,
    float* __restrict__ Cf,
    int M, int N, int K)
{
    __shared__ __align__(16) unsigned short As[2][64 * 32];
    __shared__ __align__(16) unsigned short Bs[2][128 * 32];

    const int tid  = threadIdx.x;
    const int wave = tid >> 6;
    const int lane = tid & 63;
    const int quad = lane >> 4;
    const int l16  = lane & 15;
    const int wr   = wave >> 1;
    const int wc   = wave & 1;
    const int bm   = blockIdx.y * 64;
    const int bn   = blockIdx.x * 128;
    const int bz   = blockIdx.z;

    const unsigned short* B = B0;
    unsigned short* C = C0;
    if (MODE == 1) {
        if (bz == 1)      { B = B1; C = C1; }
        else if (bz == 2) { B = B2; C = C2; }
    }

    floatx4 acc[2][4];
    const floatx4 zf = {0.f, 0.f, 0.f, 0.f};
#pragma unroll
    for (int i = 0; i < 2; ++i)
#pragma unroll
        for (int j = 0; j < 4; ++j) acc[i][j] = zf;

    const int arow0 = wave * 16 + (lane >> 2);
    const int brow0 = wave * 32 + (lane >> 2);
    const int scol  = (lane & 3) * 8;

#define GSTAGE(BUF, KB)                                                        \
    {                                                                          \
        const unsigned short* ga = A + (size_t)(bm + arow0) * K + (KB) + scol; \
        const unsigned short* gb = B + (size_t)(bn + brow0) * K + (KB) + scol; \
        gl_lds16(ga, &As[BUF][wave * 512]);                                    \
        gl_lds16(gb, &Bs[BUF][wave * 1024]);                                   \
        gl_lds16(gb + (size_t)16 * K, &Bs[BUF][wave * 1024 + 512]);            \
    }

    GSTAGE(0, 0)
    __syncthreads();          // drains vmcnt before barrier -> tile 0 ready

    int buf = 0;
    for (int kb = 0; kb < K; kb += 32) {
        if (kb + 32 < K) GSTAGE(buf ^ 1, kb + 32)   // latency hides under MFMA

        bf16x8 af[2], bfr[4];
#pragma unroll
        for (int i = 0; i < 2; ++i)
            af[i]  = *(const bf16x8*)&As[buf][(wr * 32 + i * 16 + l16) * 32 + quad * 8];
#pragma unroll
        for (int j = 0; j < 4; ++j)
            bfr[j] = *(const bf16x8*)&Bs[buf][(wc * 64 + j * 16 + l16) * 32 + quad * 8];
#pragma unroll
        for (int mi = 0; mi < 2; ++mi)
#pragma unroll
            for (int ni = 0; ni < 4; ++ni)
                acc[mi][ni] = __builtin_amdgcn_mfma_f32_16x16x32_bf16(af[mi], bfr[ni], acc[mi][ni], 0, 0, 0);

        __syncthreads();      // staged(buf^1) complete; reads of buf done
        buf ^= 1;
    }
#undef GSTAGE

    const float cscale = (MODE == 1 && bz == 0) ? QSCALE : 1.0f;

#pragma unroll
    for (int mi = 0; mi < 2; ++mi) {
#pragma unroll
        for (int ni = 0; ni < 4; ++ni) {
            const floatx4 v = acc[mi][ni];
            const int n = bn + wc * 64 + ni * 16 + l16;
            const int m0 = bm + wr * 32 + mi * 16 + quad * 4;
            if (MODE == 1 && bz == 2) {
                const int hh = n >> 6, d = n & 63;
                ushortx4 pv;
#pragma unroll
                for (int r = 0; r < 4; ++r) pv[r] = f2bf(v[r]);
                *(ushortx4*)&C[(size_t)(hh * 64 + d) * M + m0] = pv;
            } else {
#pragma unroll
                for (int r = 0; r < 4; ++r) {
                    const int m = m0 + r;
                    if (MODE == 0) {
                        Cf[(size_t)m * N + n] = v[r];
                    } else {
                        const int hh = n >> 6, d = n & 63;
                        C[((size_t)hh * M + m) * 64 + d] = f2bf(v[r] * cscale);
                    }
                }
            }
        }
    }
}

// ---------------- flash attention, 32x32 S^T formulation ----------------
// grid (WPH, NHEADS) + XCD swizzle, 256 thr = 4 waves, each wave 32 q.
// DOUBLE-buffered LDS, one barrier per tile (R12-proven).
// m_i init 0; speculative exp2 vs m_old; l_i lane-partial, merged in epilogue.
// sv C-layout (32x32x16): col q = lane&31, row kv = (r&3)+8*(r>>2)+4*(lane>>5).
__global__ __launch_bounds__(256, 4) void flash_part(
    const unsigned short* __restrict__ Qh,
    const unsigned short* __restrict__ Kh,
    const unsigned short* __restrict__ VhT,   // [H][64][S]
    unsigned short* __restrict__ AO,
    unsigned short* __restrict__ Opart,
    float* __restrict__ ml)
{
    __shared__ __align__(16) unsigned short Ks[2][64 * LDSW];   // [kv][d]
    __shared__ __align__(16) unsigned short Vs[2][64 * LDSW];   // [d][kv]

    const int tid  = threadIdx.x;
    const int wave = tid >> 6;
    const int lane = tid & 63;
    const int l31  = lane & 31;
    const int hi   = lane >> 5;     // 0/1
    const int hi8  = hi * 8;

    // XCD swizzle: blocks sharing a head's K/V land on one XCD's L2.
    int o = (int)blockIdx.y * WPH + blockIdx.x;      // nwg = 1728, %8 == 0
    o = (o & 7) * (1728 / 8) + (o >> 3);
    const int h = o / WPH;
    const int w = o % WPH;

    int c = 0;
#pragma unroll
    for (int j = 1; j < 8; ++j) c += (w >= d_coff[j]);
    const int qb = 4 * c + (w - d_coff[c]);

    const int q0       = qb * 128;
    const int kv_start = c * 512;
    const int kv_end   = min(kv_start + 512, q0 + 128);
    const int ntiles   = (kv_end - kv_start) >> 6;
    const int qbase    = q0 + wave * 32;

    const unsigned short* Qb  = Qh  + (size_t)h * S_LEN * 64;
    const unsigned short* Kb  = Kh  + (size_t)h * S_LEN * 64;
    const unsigned short* Vtb = VhT + (size_t)h * 64 * S_LEN;

    // Q B-frags: lane holds n=q=qbase+l31, k=d = dk*16 + hi8 + j
    bf16x8 qf[4];
#pragma unroll
    for (int dk = 0; dk < 4; ++dk)
        qf[dk] = *(const bf16x8*)&Qb[(size_t)(qbase + l31) * 64 + dk * 16 + hi8];

    float m_i = 0.f, l_i = 0.f;   // m starts at 0 (defer bound keeps p <= 2^11.54)
    floatx16 o0, o1;    // O cols d 0-31 / 32-63; rows q per C-layout
#pragma unroll
    for (int r = 0; r < 16; ++r) { o0[r] = 0.f; o1[r] = 0.f; }

    const int srow = tid >> 2;           // 0..63
    const int scol = (tid & 3) * 16;     // 0,16,32,48

    // prologue: stage tile 0 into buf 0
    {
        const unsigned short* kp = Kb + (size_t)(kv_start + srow) * 64 + scol;
        const unsigned short* vp = Vtb + (size_t)srow * S_LEN + kv_start + scol;
        const ushortx8 k0 = *(const ushortx8*)kp;
        const ushortx8 k1 = *(const ushortx8*)(kp + 8);
        const ushortx8 v0 = *(const ushortx8*)vp;
        const ushortx8 v1 = *(const ushortx8*)(vp + 8);
        *(ushortx8*)&Ks[0][srow * LDSW + scol]     = k0;
        *(ushortx8*)&Ks[0][srow * LDSW + scol + 8] = k1;
        *(ushortx8*)&Vs[0][srow * LDSW + scol]     = v0;
        *(ushortx8*)&Vs[0][srow * LDSW + scol + 8] = v1;
    }
    __syncthreads();

    for (int t = 0; t < ntiles; ++t) {
        const int buf = t & 1;
        const int kv0 = kv_start + t * 64;
        const bool pre = (t + 1 < ntiles);

        ushortx8 kr0, kr1, vr0, vr1;
        if (pre) {
            const unsigned short* kp = Kb + (size_t)(kv0 + 64 + srow) * 64 + scol;
            const unsigned short* vp = Vtb + (size_t)srow * S_LEN + kv0 + 64 + scol;
            kr0 = *(const ushortx8*)kp;  kr1 = *(const ushortx8*)(kp + 8);
            vr0 = *(const ushortx8*)vp;  vr1 = *(const ushortx8*)(vp + 8);
        }

        if (kv0 <= qbase + 31) {   // wave has unmasked work in this tile
            // S^T = K Q^T : two 32x32 outputs (kv rows 0-31 / 32-63)
            floatx16 sv0, sv1;
#pragma unroll
            for (int r = 0; r < 16; ++r) { sv0[r] = 0.f; sv1[r] = 0.f; }
            __builtin_amdgcn_s_setprio(1);
#pragma unroll
            for (int dk = 0; dk < 4; ++dk) {
                const bf16x8 kf0 = *(const bf16x8*)&Ks[buf][(l31)      * LDSW + dk * 16 + hi8];
                const bf16x8 kf1 = *(const bf16x8*)&Ks[buf][(32 + l31) * LDSW + dk * 16 + hi8];
                sv0 = __builtin_amdgcn_mfma_f32_32x32x16_bf16(kf0, qf[dk], sv0, 0, 0, 0);
                sv1 = __builtin_amdgcn_mfma_f32_32x32x16_bf16(kf1, qf[dk], sv1, 0, 0, 0);
            }
            __builtin_amdgcn_s_setprio(0);

            const int qcol = qbase + l31;
            if (kv0 + 63 > qbase) {     // causal mask needed
#pragma unroll
                for (int r = 0; r < 16; ++r) {
                    const int kvo = (r & 3) + 8 * (r >> 2) + 4 * hi;
                    if (kv0 + kvo > qcol)      sv0[r] = -1e9f;
                    if (kv0 + 32 + kvo > qcol) sv1[r] = -1e9f;
                }
            }

            const float m_old = m_i;
            // local max tree (reads sv BEFORE the destructive exp2)
            float a_[8];
#pragma unroll
            for (int g = 0; g < 8; ++g)
                a_[g] = fmaxf(fmaxf(sv0[2*g], sv0[2*g+1]), fmaxf(sv1[2*g], sv1[2*g+1]));
            float mx = fmaxf(fmaxf(fmaxf(a_[0], a_[1]), fmaxf(a_[2], a_[3])),
                             fmaxf(fmaxf(a_[4], a_[5]), fmaxf(a_[6], a_[7])));
            // speculative exp2 vs m_old — issues now, overlaps the shfl chain
#pragma unroll
            for (int r = 0; r < 16; ++r) {
                sv0[r] = EXP2(sv0[r] - m_old);
                sv1[r] = EXP2(sv1[r] - m_old);
            }
            mx = fmaxf(mx, __shfl_xor(mx, 32, 64));
            const bool defer = (__all(mx <= m_old + 11.541560327f) != 0);
            float al = 1.f;
            if (!defer) {
                const float mn = fmaxf(m_old, mx);
                al = EXP2(m_old - mn);
                m_i = mn;
#pragma unroll
                for (int r = 0; r < 16; ++r) { sv0[r] *= al; sv1[r] *= al; }
            }
            // lane-partial row sum (NO per-tile shfl; merged in epilogue)
            float s_[8];
#pragma unroll
            for (int g = 0; g < 8; ++g)
                s_[g] = (sv0[2*g] + sv0[2*g+1]) + (sv1[2*g] + sv1[2*g+1]);
            const float rs = ((s_[0] + s_[1]) + (s_[2] + s_[3])) + ((s_[4] + s_[5]) + (s_[6] + s_[7]));
            l_i = (defer ? l_i : l_i * al) + rs;

            // pack P pairs (kv 2g,2g+1) to bf16 RNE (v_cvt_pk-fusible)
            unsigned pk0[8], pk1[8];
#pragma unroll
            for (int g = 0; g < 8; ++g) {
                pk0[g] = pack2bf(sv0[2*g], sv0[2*g+1]);
                pk1[g] = pack2bf(sv1[2*g], sv1[2*g+1]);
            }

            if (!defer) {
                // rescale O rows; row q_local = (r&3)+8*(r>>2)+4*hi
#pragma unroll
                for (int r = 0; r < 16; ++r) {
                    const float a = __shfl(al, (r & 3) + 8 * (r >> 2) + 4 * hi, 64);
                    o0[r] *= a; o1[r] *= a;
                }
            }

            // O += P V: A-frag per kt (kv 16-block) via 2 permlane32_swap.
            __builtin_amdgcn_s_setprio(1);
#define PV_STEP(PK, KPAR, KT)                                                  \
            {                                                                  \
                uintx2 rA = plane32_swap(PK[(KPAR)*4 + 0], PK[(KPAR)*4 + 2]);  \
                uintx2 rB = plane32_swap(PK[(KPAR)*4 + 1], PK[(KPAR)*4 + 3]);  \
                uintx4 aw; aw[0] = rA[0]; aw[1] = rB[0]; aw[2] = rA[1]; aw[3] = rB[1]; \
                const bf16x8 paf = __builtin_bit_cast(bf16x8, aw);             \
                const int kvcol = (KT) * 16 + hi8;                             \
                const bf16x8 vf0 = *(const bf16x8*)&Vs[buf][(l31)      * LDSW + kvcol]; \
                const bf16x8 vf1 = *(const bf16x8*)&Vs[buf][(32 + l31) * LDSW + kvcol]; \
                o0 = __builtin_amdgcn_mfma_f32_32x32x16_bf16(paf, vf0, o0, 0, 0, 0);    \
                o1 = __builtin_amdgcn_mfma_f32_32x32x16_bf16(paf, vf1, o1, 0, 0, 0);    \
            }
            PV_STEP(pk0, 0, 0)
            PV_STEP(pk0, 1, 1)
            PV_STEP(pk1, 0, 2)
            PV_STEP(pk1, 1, 3)
#undef PV_STEP
            __builtin_amdgcn_s_setprio(0);
        }

        if (pre) {
            *(ushortx8*)&Ks[buf ^ 1][srow * LDSW + scol]     = kr0;
            *(ushortx8*)&Ks[buf ^ 1][srow * LDSW + scol + 8] = kr1;
            *(ushortx8*)&Vs[buf ^ 1][srow * LDSW + scol]     = vr0;
            *(ushortx8*)&Vs[buf ^ 1][srow * LDSW + scol + 8] = vr1;
        }
        __syncthreads();
    }

    // merge the lane-partial row sums (halves of kv live in lanes l, l+32)
    const float l_tot = l_i + __shfl_xor(l_i, 32, 64);

    // epilogue. O: col d = dblk*32 + l31, row q_local = (r&3)+8*(r>>2)+4*hi
    if (qb < 4) {
        const float invl = 1.0f / l_tot;
#pragma unroll
        for (int r = 0; r < 16; ++r) {
            const int ql = (r & 3) + 8 * (r >> 2) + 4 * hi;
            const float a = __shfl(invl, ql, 64);
            const int qr = qbase + ql;
            AO[(size_t)qr * DMODEL + h * 64 + l31]      = f2bf(o0[r] * a);
            AO[(size_t)qr * DMODEL + h * 64 + 32 + l31] = f2bf(o1[r] * a);
        }
    } else {
        const int slot = h * WPH + w;
        unsigned short* op = Opart + (size_t)slot * (128 * 64);
#pragma unroll
        for (int r = 0; r < 16; ++r) {
            const int ql = (r & 3) + 8 * (r >> 2) + 4 * hi;
            const int lr = wave * 32 + ql;
            op[lr * 64 + l31]      = f2bf(o0[r]);
            op[lr * 64 + 32 + l31] = f2bf(o1[r]);
        }
        if (hi == 0) {
            float* mlp = ml + (size_t)slot * 256;
            const int lr = wave * 32 + l31;
            mlp[lr * 2]     = m_i;
            mlp[lr * 2 + 1] = l_tot;
        }
    }
}

// ---------------- combine chunk partials (exp2 domain) ----------------
__global__ __launch_bounds__(256) void combine(
    const unsigned short* __restrict__ Opart,
    const float* __restrict__ ml,
    unsigned short* __restrict__ AO)
{
    const int qb  = 4 + blockIdx.x;          // qb in [4, 32)
    const int h   = blockIdx.y;
    const int row = threadIdx.x >> 1;
    const int ds  = (threadIdx.x & 1) * 32;
    const int nc  = (qb >> 2) + 1;           // chunks for this qb (2..8)

    int slots[8];
    for (int cI = 0; cI < 8; ++cI) slots[cI] = h * WPH + d_coff[cI] + (qb - 4 * cI);

    float mc[8], lc[8];
    float M = -3e38f;
    for (int cI = 0; cI < nc; ++cI) {
        mc[cI] = ml[(size_t)slots[cI] * 256 + row * 2];
        lc[cI] = ml[(size_t)slots[cI] * 256 + row * 2 + 1];
        M = fmaxf(M, mc[cI]);
    }
    float L = 0.f;
    float acc[32];
#pragma unroll
    for (int i = 0; i < 32; ++i) acc[i] = 0.f;

    for (int cI = 0; cI < nc; ++cI) {
        const float sc = EXP2(mc[cI] - M);
        L += sc * lc[cI];
        const unsigned short* op = Opart + (size_t)slots[cI] * (128 * 64) + row * 64 + ds;
#pragma unroll
        for (int g = 0; g < 4; ++g) {
            const ushortx8 a = *(const ushortx8*)(op + g * 8);
#pragma unroll
            for (int i = 0; i < 8; ++i) acc[g * 8 + i] += sc * bf2f(a[i]);
        }
    }
    const float inv = 1.0f / L;
    unsigned short* dst = AO + (size_t)(qb * 128 + row) * DMODEL + h * 64 + ds;
#pragma unroll
    for (int g = 0; g < 4; ++g) {
        ushortx8 ov;
#pragma unroll
        for (int i = 0; i < 8; ++i) ov[i] = f2bf(acc[g * 8 + i] * inv);
        *(ushortx8*)(dst + g * 8) = ov;
    }
}

extern "C" void kernel_launch(void* const* d_in, const int* in_sizes, int n_in,
                              void* d_out, int out_size, void* d_ws, size_t ws_size,
                              hipStream_t stream) {
    const float* x  = (const float*)d_in[0];
    const float* Wq = (const float*)d_in[1];
    const float* Wk = (const float*)d_in[2];
    const float* Wv = (const float*)d_in[3];
    const float* Wo = (const float*)d_in[4];

    const int xElems = S_LEN * DMODEL;
    const int wElems = DMODEL * DMODEL;
    const size_t headElems = (size_t)NHEADS * S_LEN * 64;
    const int nslots = NHEADS * WPH;   // 1728

    unsigned short* xb  = (unsigned short*)d_ws;
    unsigned short* Wqb = xb  + xElems;
    unsigned short* Wkb = Wqb + wElems;
    unsigned short* Wvb = Wkb + wElems;
    unsigned short* Wob = Wvb + wElems;
    unsigned short* Qh  = Wob + wElems;
    unsigned short* Kh  = Qh + headElems;
    unsigned short* Vt  = Kh + headElems;                    // [H][64][S]
    unsigned short* AO  = Vt + headElems;
    unsigned short* Opart = AO + xElems;                     // [1728][128*64]
    float* ml = (float*)(Opart + (size_t)nslots * 128 * 64); // [1728][256]

    cvt_all<<<dim3(2688), dim3(256), 0, stream>>>(x, Wq, Wk, Wv, Wo,
                                                  xb, Wqb, Wkb, Wvb, Wob);

    gemm_nt<1><<<dim3(DMODEL / 128, S_LEN / 64, 3), dim3(256), 0, stream>>>(
        xb, Wqb, Wkb, Wvb, Qh, Kh, Vt, nullptr, S_LEN, DMODEL, DMODEL);

    flash_part<<<dim3(WPH, NHEADS), dim3(256), 0, stream>>>(Qh, Kh, Vt, AO, Opart, ml);

    combine<<<dim3(28, NHEADS), dim3(256), 0, stream>>>(Opart, ml, AO);

    gemm_nt<0><<<dim3(DMODEL / 128, S_LEN / 64, 1), dim3(256), 0, stream>>>(
        AO, Wob, nullptr, nullptr, nullptr, nullptr, nullptr,
        (float*)d_out, S_LEN, DMODEL, DMODEL);
}

// Round 15
// 183.729 us; speedup vs baseline: 1.1394x; 1.0190x over previous
//
#include <hip/hip_runtime.h>
#include <hip/hip_bf16.h>
#include <stdint.h>

// MultiHeadSelfAttention, B=1, S=4096, D_MODEL=768, H=12, Dk=64, causal.
// FP32 I/O, bf16 MFMA inside. Launches:
//   0) cvt_all    fp32->bf16
//   1) gemm_nt<1> QKV projections -> Q,K [H][S][64] bf16, V TRANSPOSED [H][64][S]
//        Q is pre-scaled by 0.125*log2(e) so flash softmax runs in exp2 domain.
//   2) flash_part causal flash attention, 32x32 S^T formulation, KV chunks 512
//   3) combine    merge chunk partials -> AO (exp2 domain)
//   4) gemm_nt<0> AO @ Wo^T -> d_out fp32
// R11: flash 32x32 MFMA + permlane32_swap (83.6->56.2us).
// R12: flash XCD swizzle kept. R17: V-from-global regressed (uncoalesced).
// R15-R19: plateau 187.2-189.4us; flash 55-58; gemm dbuf (R19) tied-best,
//      kept. Non-flash ~129us; gemms ~75-80 of it (latency-bound: 110cyc
//      compute vs ~500cyc load per K-step).
// R20 (this round): gemm BK 32->64. Halves latency-exposed steps (24->12),
//      doubles per-step MFMA (8->16). K stored as TWO 32-col panels (64B
//      row stride, proven 8-way-conflict pattern; flat [64][64] would be
//      16-way). Panel selection via per-lane GLOBAL addr; LDS dest linear
//      for gl_lds. LDS 24->48KB (3 blocks/CU). Flash unchanged.

#define S_LEN  4096
#define DMODEL 768
#define NHEADS 12
#define LDSW   72          // padded LDS row stride (elems); 144B = 16B-aligned
#define WPH    144         // work items per head: 32+28+24+20+16+12+8+4
#define QSCALE 0.1803368801111437f   // 0.125 * log2(e)

typedef __attribute__((ext_vector_type(8))) __bf16 bf16x8;
typedef __attribute__((ext_vector_type(8))) unsigned short ushortx8;
typedef __attribute__((ext_vector_type(4))) unsigned short ushortx4;
typedef __attribute__((ext_vector_type(4))) unsigned int uintx4;
typedef __attribute__((ext_vector_type(2))) unsigned int uintx2;
typedef __attribute__((ext_vector_type(4))) float floatx4;
typedef __attribute__((ext_vector_type(16))) float floatx16;

__device__ __forceinline__ unsigned short f2bf(float f) {
    unsigned int u = __float_as_uint(f);
    u += 0x7fffu + ((u >> 16) & 1u);   // RNE
    return (unsigned short)(u >> 16);
}
__device__ __forceinline__ float bf2f(unsigned short v) {
    return __uint_as_float(((unsigned int)v) << 16);
}
// pack two f32 -> one dword of 2 bf16 (RNE); compiler fuses to v_cvt_pk_bf16_f32
__device__ __forceinline__ unsigned pack2bf(float lo, float hi) {
    const unsigned short ul = __builtin_bit_cast(unsigned short, (__bf16)lo);
    const unsigned short uh = __builtin_bit_cast(unsigned short, (__bf16)hi);
    return ((unsigned)uh << 16) | ul;
}

#if defined(__has_builtin)
#if __has_builtin(__builtin_amdgcn_exp2f)
#define EXP2(x) __builtin_amdgcn_exp2f(x)
#endif
#endif
#ifndef EXP2
#define EXP2(x) exp2f(x)
#endif

// v_permlane32_swap_b32: vdst[32:63] <-> vsrc[0:31].
__device__ __forceinline__ uintx2 plane32_swap(unsigned a, unsigned b) {
#if defined(__has_builtin) && __has_builtin(__builtin_amdgcn_permlane32_swap)
    auto r = __builtin_amdgcn_permlane32_swap(a, b, false, false);
    uintx2 out; out[0] = (unsigned)r[0]; out[1] = (unsigned)r[1];
    return out;
#else
    const int lane = (int)(threadIdx.x & 63);
    const unsigned as = (unsigned)__shfl_xor((int)a, 32, 64);
    const unsigned bs = (unsigned)__shfl_xor((int)b, 32, 64);
    uintx2 out;
    out[0] = (lane >= 32) ? bs : a;
    out[1] = (lane >= 32) ? b : as;
    return out;
#endif
}

// direct global->LDS copy, 16B/lane; lptr is the WAVE-UNIFORM base.
__device__ __forceinline__ void gl_lds16(const void* g, void* l) {
    __builtin_amdgcn_global_load_lds(
        (const __attribute__((address_space(1))) unsigned int*)g,
        (__attribute__((address_space(3))) unsigned int*)l,
        16, 0, 0);
}

// chunk offsets: chunk c covers qb in [4c, 32), count 32-4c
__device__ __constant__ int d_coff[9] = {0, 32, 60, 84, 104, 120, 132, 140, 144};

// ---------------- fused fp32->bf16 conversion ----------------
__global__ __launch_bounds__(256) void cvt_all(
    const float* __restrict__ x,  const float* __restrict__ Wq,
    const float* __restrict__ Wk, const float* __restrict__ Wv,
    const float* __restrict__ Wo,
    unsigned short* __restrict__ xb,  unsigned short* __restrict__ Wqb,
    unsigned short* __restrict__ Wkb, unsigned short* __restrict__ Wvb,
    unsigned short* __restrict__ Wob)
{
    int b = blockIdx.x;
    const float* src; unsigned short* dst;
    if (b < 1536)      { src = x;  dst = xb;  }
    else if (b < 1824) { src = Wq; dst = Wqb; b -= 1536; }
    else if (b < 2112) { src = Wk; dst = Wkb; b -= 1824; }
    else if (b < 2400) { src = Wv; dst = Wvb; b -= 2112; }
    else               { src = Wo; dst = Wob; b -= 2400; }
    const int i = (b * 256 + threadIdx.x) * 8;
    const float4 a0 = *(const float4*)(src + i);
    const float4 a1 = *(const float4*)(src + i + 4);
    ushortx8 o;
    o[0] = f2bf(a0.x); o[1] = f2bf(a0.y); o[2] = f2bf(a0.z); o[3] = f2bf(a0.w);
    o[4] = f2bf(a1.x); o[5] = f2bf(a1.y); o[6] = f2bf(a1.z); o[7] = f2bf(a1.w);
    *(ushortx8*)(dst + i) = o;
}

// ---------------- GEMM C = A * B^T, tile 64M x 128N, BK=64 ----------------
// MODE 0: fp32 out [M][N]. MODE 1: z=0 Q (scaled by QSCALE), z=1 K,
// head-major [H][M][64]; z=2 V TRANSPOSED: C2[(h*64+d)*M + m], b64 stores.
// 16x16x32 MFMA. K=64 per step held as TWO 32-col panels (64B stride each).
// Double-buffered gl_lds staging, one barrier per K-step.
template <int MODE>
__global__ __launch_bounds__(256) void gemm_nt(
    const unsigned short* __restrict__ A,
    const unsigned short* __restrict__ B0,
    const unsigned short* __restrict__ B1,
    const unsigned short* __restrict__ B2,
    unsigned short* __restrict__ C0,
    unsigned short* __restrict__ C1,
    unsigned short* __restrict__ C2,
    float* __restrict__ Cf,
    int M, int N, int K)
{
    __shared__ __align__(16) unsigned short As[2][2][64 * 32];    // [buf][panel]
    __shared__ __align__(16) unsigned short Bs[2][2][128 * 32];

    const int tid  = threadIdx.x;
    const int wave = tid >> 6;
    const int lane = tid & 63;
    const int quad = lane >> 4;
    const int l16  = lane & 15;
    const int wr   = wave >> 1;
    const int wc   = wave & 1;
    const int bm   = blockIdx.y * 64;
    const int bn   = blockIdx.x * 128;
    const int bz   = blockIdx.z;

    const unsigned short* B = B0;
    unsigned short* C = C0;
    if (MODE == 1) {
        if (bz == 1)      { B = B1; C = C1; }
        else if (bz == 2) { B = B2; C = C2; }
    }

    floatx4 acc[2][4];
    const floatx4 zf = {0.f, 0.f, 0.f, 0.f};
#pragma unroll
    for (int i = 0; i < 2; ++i)
#pragma unroll
        for (int j = 0; j < 4; ++j) acc[i][j] = zf;

    // staging maps (gl_lds: wave-uniform LDS base + lane*16B; global addr
    // per-lane picks the panel layout):
    // A panel p (64x32): lane l -> row wave*16+(l>>2), col p*32+(l&3)*8
    // B panel p (128x32): lane l -> rows wave*32+(l>>2) (+16), same cols
    const int arow0 = wave * 16 + (lane >> 2);
    const int brow0 = wave * 32 + (lane >> 2);
    const int scol  = (lane & 3) * 8;

#define GSTAGE(BUF, KB)                                                        \
    {                                                                          \
        _Pragma("unroll")                                                      \
        for (int p = 0; p < 2; ++p) {                                          \
            const unsigned short* ga = A + (size_t)(bm + arow0) * K + (KB) + p * 32 + scol; \
            const unsigned short* gb = B + (size_t)(bn + brow0) * K + (KB) + p * 32 + scol; \
            gl_lds16(ga, &As[BUF][p][wave * 512]);                             \
            gl_lds16(gb, &Bs[BUF][p][wave * 1024]);                            \
            gl_lds16(gb + (size_t)16 * K, &Bs[BUF][p][wave * 1024 + 512]);     \
        }                                                                      \
    }

    GSTAGE(0, 0)
    __syncthreads();          // drains vmcnt -> tile 0 ready

    int buf = 0;
    for (int kb = 0; kb < K; kb += 64) {
        if (kb + 64 < K) GSTAGE(buf ^ 1, kb + 64)   // latency hides under MFMA

#pragma unroll
        for (int kc = 0; kc < 2; ++kc) {
            bf16x8 af[2], bfr[4];
#pragma unroll
            for (int i = 0; i < 2; ++i)
                af[i]  = *(const bf16x8*)&As[buf][kc][(wr * 32 + i * 16 + l16) * 32 + quad * 8];
#pragma unroll
            for (int j = 0; j < 4; ++j)
                bfr[j] = *(const bf16x8*)&Bs[buf][kc][(wc * 64 + j * 16 + l16) * 32 + quad * 8];
#pragma unroll
            for (int mi = 0; mi < 2; ++mi)
#pragma unroll
                for (int ni = 0; ni < 4; ++ni)
                    acc[mi][ni] = __builtin_amdgcn_mfma_f32_16x16x32_bf16(af[mi], bfr[ni], acc[mi][ni], 0, 0, 0);
        }

        __syncthreads();      // staged(buf^1) complete; reads of buf done
        buf ^= 1;
    }
#undef GSTAGE

    const float cscale = (MODE == 1 && bz == 0) ? QSCALE : 1.0f;

#pragma unroll
    for (int mi = 0; mi < 2; ++mi) {
#pragma unroll
        for (int ni = 0; ni < 4; ++ni) {
            const floatx4 v = acc[mi][ni];
            const int n = bn + wc * 64 + ni * 16 + l16;
            const int m0 = bm + wr * 32 + mi * 16 + quad * 4;
            if (MODE == 1 && bz == 2) {
                const int hh = n >> 6, d = n & 63;
                ushortx4 pv;
#pragma unroll
                for (int r = 0; r < 4; ++r) pv[r] = f2bf(v[r]);
                *(ushortx4*)&C[(size_t)(hh * 64 + d) * M + m0] = pv;
            } else {
#pragma unroll
                for (int r = 0; r < 4; ++r) {
                    const int m = m0 + r;
                    if (MODE == 0) {
                        Cf[(size_t)m * N + n] = v[r];
                    } else {
                        const int hh = n >> 6, d = n & 63;
                        C[((size_t)hh * M + m) * 64 + d] = f2bf(v[r] * cscale);
                    }
                }
            }
        }
    }
}

// ---------------- flash attention, 32x32 S^T formulation ----------------
// grid (WPH, NHEADS) + XCD swizzle, 256 thr = 4 waves, each wave 32 q.
// DOUBLE-buffered LDS, one barrier per tile (R12-proven).
// m_i init 0; speculative exp2 vs m_old; l_i lane-partial, merged in epilogue.
// sv C-layout (32x32x16): col q = lane&31, row kv = (r&3)+8*(r>>2)+4*(lane>>5).
__global__ __launch_bounds__(256, 4) void flash_part(
    const unsigned short* __restrict__ Qh,
    const unsigned short* __restrict__ Kh,
    const unsigned short* __restrict__ VhT,   // [H][64][S]
    unsigned short* __restrict__ AO,
    unsigned short* __restrict__ Opart,
    float* __restrict__ ml)
{
    __shared__ __align__(16) unsigned short Ks[2][64 * LDSW];   // [kv][d]
    __shared__ __align__(16) unsigned short Vs[2][64 * LDSW];   // [d][kv]

    const int tid  = threadIdx.x;
    const int wave = tid >> 6;
    const int lane = tid & 63;
    const int l31  = lane & 31;
    const int hi   = lane >> 5;     // 0/1
    const int hi8  = hi * 8;

    // XCD swizzle: blocks sharing a head's K/V land on one XCD's L2.
    int o = (int)blockIdx.y * WPH + blockIdx.x;      // nwg = 1728, %8 == 0
    o = (o & 7) * (1728 / 8) + (o >> 3);
    const int h = o / WPH;
    const int w = o % WPH;

    int c = 0;
#pragma unroll
    for (int j = 1; j < 8; ++j) c += (w >= d_coff[j]);
    const int qb = 4 * c + (w - d_coff[c]);

    const int q0       = qb * 128;
    const int kv_start = c * 512;
    const int kv_end   = min(kv_start + 512, q0 + 128);
    const int ntiles   = (kv_end - kv_start) >> 6;
    const int qbase    = q0 + wave * 32;

    const unsigned short* Qb  = Qh  + (size_t)h * S_LEN * 64;
    const unsigned short* Kb  = Kh  + (size_t)h * S_LEN * 64;
    const unsigned short* Vtb = VhT + (size_t)h * 64 * S_LEN;

    // Q B-frags: lane holds n=q=qbase+l31, k=d = dk*16 + hi8 + j
    bf16x8 qf[4];
#pragma unroll
    for (int dk = 0; dk < 4; ++dk)
        qf[dk] = *(const bf16x8*)&Qb[(size_t)(qbase + l31) * 64 + dk * 16 + hi8];

    float m_i = 0.f, l_i = 0.f;   // m starts at 0 (defer bound keeps p <= 2^11.54)
    floatx16 o0, o1;    // O cols d 0-31 / 32-63; rows q per C-layout
#pragma unroll
    for (int r = 0; r < 16; ++r) { o0[r] = 0.f; o1[r] = 0.f; }

    const int srow = tid >> 2;           // 0..63
    const int scol = (tid & 3) * 16;     // 0,16,32,48

    // prologue: stage tile 0 into buf 0
    {
        const unsigned short* kp = Kb + (size_t)(kv_start + srow) * 64 + scol;
        const unsigned short* vp = Vtb + (size_t)srow * S_LEN + kv_start + scol;
        const ushortx8 k0 = *(const ushortx8*)kp;
        const ushortx8 k1 = *(const ushortx8*)(kp + 8);
        const ushortx8 v0 = *(const ushortx8*)vp;
        const ushortx8 v1 = *(const ushortx8*)(vp + 8);
        *(ushortx8*)&Ks[0][srow * LDSW + scol]     = k0;
        *(ushortx8*)&Ks[0][srow * LDSW + scol + 8] = k1;
        *(ushortx8*)&Vs[0][srow * LDSW + scol]     = v0;
        *(ushortx8*)&Vs[0][srow * LDSW + scol + 8] = v1;
    }
    __syncthreads();

    for (int t = 0; t < ntiles; ++t) {
        const int buf = t & 1;
        const int kv0 = kv_start + t * 64;
        const bool pre = (t + 1 < ntiles);

        ushortx8 kr0, kr1, vr0, vr1;
        if (pre) {
            const unsigned short* kp = Kb + (size_t)(kv0 + 64 + srow) * 64 + scol;
            const unsigned short* vp = Vtb + (size_t)srow * S_LEN + kv0 + 64 + scol;
            kr0 = *(const ushortx8*)kp;  kr1 = *(const ushortx8*)(kp + 8);
            vr0 = *(const ushortx8*)vp;  vr1 = *(const ushortx8*)(vp + 8);
        }

        if (kv0 <= qbase + 31) {   // wave has unmasked work in this tile
            // S^T = K Q^T : two 32x32 outputs (kv rows 0-31 / 32-63)
            floatx16 sv0, sv1;
#pragma unroll
            for (int r = 0; r < 16; ++r) { sv0[r] = 0.f; sv1[r] = 0.f; }
            __builtin_amdgcn_s_setprio(1);
#pragma unroll
            for (int dk = 0; dk < 4; ++dk) {
                const bf16x8 kf0 = *(const bf16x8*)&Ks[buf][(l31)      * LDSW + dk * 16 + hi8];
                const bf16x8 kf1 = *(const bf16x8*)&Ks[buf][(32 + l31) * LDSW + dk * 16 + hi8];
                sv0 = __builtin_amdgcn_mfma_f32_32x32x16_bf16(kf0, qf[dk], sv0, 0, 0, 0);
                sv1 = __builtin_amdgcn_mfma_f32_32x32x16_bf16(kf1, qf[dk], sv1, 0, 0, 0);
            }
            __builtin_amdgcn_s_setprio(0);

            const int qcol = qbase + l31;
            if (kv0 + 63 > qbase) {     // causal mask needed
#pragma unroll
                for (int r = 0; r < 16; ++r) {
                    const int kvo = (r & 3) + 8 * (r >> 2) + 4 * hi;
                    if (kv0 + kvo > qcol)      sv0[r] = -1e9f;
                    if (kv0 + 32 + kvo > qcol) sv1[r] = -1e9f;
                }
            }

            const float m_old = m_i;
            // local max tree (reads sv BEFORE the destructive exp2)
            float a_[8];
#pragma unroll
            for (int g = 0; g < 8; ++g)
                a_[g] = fmaxf(fmaxf(sv0[2*g], sv0[2*g+1]), fmaxf(sv1[2*g], sv1[2*g+1]));
            float mx = fmaxf(fmaxf(fmaxf(a_[0], a_[1]), fmaxf(a_[2], a_[3])),
                             fmaxf(fmaxf(a_[4], a_[5]), fmaxf(a_[6], a_[7])));
            // speculative exp2 vs m_old — issues now, overlaps the shfl chain
#pragma unroll
            for (int r = 0; r < 16; ++r) {
                sv0[r] = EXP2(sv0[r] - m_old);
                sv1[r] = EXP2(sv1[r] - m_old);
            }
            mx = fmaxf(mx, __shfl_xor(mx, 32, 64));
            const bool defer = (__all(mx <= m_old + 11.541560327f) != 0);
            float al = 1.f;
            if (!defer) {
                const float mn = fmaxf(m_old, mx);
                al = EXP2(m_old - mn);
                m_i = mn;
#pragma unroll
                for (int r = 0; r < 16; ++r) { sv0[r] *= al; sv1[r] *= al; }
            }
            // lane-partial row sum (NO per-tile shfl; merged in epilogue)
            float s_[8];
#pragma unroll
            for (int g = 0; g < 8; ++g)
                s_[g] = (sv0[2*g] + sv0[2*g+1]) + (sv1[2*g] + sv1[2*g+1]);
            const float rs = ((s_[0] + s_[1]) + (s_[2] + s_[3])) + ((s_[4] + s_[5]) + (s_[6] + s_[7]));
            l_i = (defer ? l_i : l_i * al) + rs;

            // pack P pairs (kv 2g,2g+1) to bf16 RNE (v_cvt_pk-fusible)
            unsigned pk0[8], pk1[8];
#pragma unroll
            for (int g = 0; g < 8; ++g) {
                pk0[g] = pack2bf(sv0[2*g], sv0[2*g+1]);
                pk1[g] = pack2bf(sv1[2*g], sv1[2*g+1]);
            }

            if (!defer) {
                // rescale O rows; row q_local = (r&3)+8*(r>>2)+4*hi
#pragma unroll
                for (int r = 0; r < 16; ++r) {
                    const float a = __shfl(al, (r & 3) + 8 * (r >> 2) + 4 * hi, 64);
                    o0[r] *= a; o1[r] *= a;
                }
            }

            // O += P V: A-frag per kt (kv 16-block) via 2 permlane32_swap.
            __builtin_amdgcn_s_setprio(1);
#define PV_STEP(PK, KPAR, KT)                                                  \
            {                                                                  \
                uintx2 rA = plane32_swap(PK[(KPAR)*4 + 0], PK[(KPAR)*4 + 2]);  \
                uintx2 rB = plane32_swap(PK[(KPAR)*4 + 1], PK[(KPAR)*4 + 3]);  \
                uintx4 aw; aw[0] = rA[0]; aw[1] = rB[0]; aw[2] = rA[1]; aw[3] = rB[1]; \
                const bf16x8 paf = __builtin_bit_cast(bf16x8, aw);             \
                const int kvcol = (KT) * 16 + hi8;                             \
                const bf16x8 vf0 = *(const bf16x8*)&Vs[buf][(l31)      * LDSW + kvcol]; \
                const bf16x8 vf1 = *(const bf16x8*)&Vs[buf][(32 + l31) * LDSW + kvcol]; \
                o0 = __builtin_amdgcn_mfma_f32_32x32x16_bf16(paf, vf0, o0, 0, 0, 0);    \
                o1 = __builtin_amdgcn_mfma_f32_32x32x16_bf16(paf, vf1, o1, 0, 0, 0);    \
            }
            PV_STEP(pk0, 0, 0)
            PV_STEP(pk0, 1, 1)
            PV_STEP(pk1, 0, 2)
            PV_STEP(pk1, 1, 3)
#undef PV_STEP
            __builtin_amdgcn_s_setprio(0);
        }

        if (pre) {
            *(ushortx8*)&Ks[buf ^ 1][srow * LDSW + scol]     = kr0;
            *(ushortx8*)&Ks[buf ^ 1][srow * LDSW + scol + 8] = kr1;
            *(ushortx8*)&Vs[buf ^ 1][srow * LDSW + scol]     = vr0;
            *(ushortx8*)&Vs[buf ^ 1][srow * LDSW + scol + 8] = vr1;
        }
        __syncthreads();
    }

    // merge the lane-partial row sums (halves of kv live in lanes l, l+32)
    const float l_tot = l_i + __shfl_xor(l_i, 32, 64);

    // epilogue. O: col d = dblk*32 + l31, row q_local = (r&3)+8*(r>>2)+4*hi
    if (qb < 4) {
        const float invl = 1.0f / l_tot;
#pragma unroll
        for (int r = 0; r < 16; ++r) {
            const int ql = (r & 3) + 8 * (r >> 2) + 4 * hi;
            const float a = __shfl(invl, ql, 64);
            const int qr = qbase + ql;
            AO[(size_t)qr * DMODEL + h * 64 + l31]      = f2bf(o0[r] * a);
            AO[(size_t)qr * DMODEL + h * 64 + 32 + l31] = f2bf(o1[r] * a);
        }
    } else {
        const int slot = h * WPH + w;
        unsigned short* op = Opart + (size_t)slot * (128 * 64);
#pragma unroll
        for (int r = 0; r < 16; ++r) {
            const int ql = (r & 3) + 8 * (r >> 2) + 4 * hi;
            const int lr = wave * 32 + ql;
            op[lr * 64 + l31]      = f2bf(o0[r]);
            op[lr * 64 + 32 + l31] = f2bf(o1[r]);
        }
        if (hi == 0) {
            float* mlp = ml + (size_t)slot * 256;
            const int lr = wave * 32 + l31;
            mlp[lr * 2]     = m_i;
            mlp[lr * 2 + 1] = l_tot;
        }
    }
}

// ---------------- combine chunk partials (exp2 domain) ----------------
__global__ __launch_bounds__(256) void combine(
    const unsigned short* __restrict__ Opart,
    const float* __restrict__ ml,
    unsigned short* __restrict__ AO)
{
    const int qb  = 4 + blockIdx.x;          // qb in [4, 32)
    const int h   = blockIdx.y;
    const int row = threadIdx.x >> 1;
    const int ds  = (threadIdx.x & 1) * 32;
    const int nc  = (qb >> 2) + 1;           // chunks for this qb (2..8)

    int slots[8];
    for (int cI = 0; cI < 8; ++cI) slots[cI] = h * WPH + d_coff[cI] + (qb - 4 * cI);

    float mc[8], lc[8];
    float M = -3e38f;
    for (int cI = 0; cI < nc; ++cI) {
        mc[cI] = ml[(size_t)slots[cI] * 256 + row * 2];
        lc[cI] = ml[(size_t)slots[cI] * 256 + row * 2 + 1];
        M = fmaxf(M, mc[cI]);
    }
    float L = 0.f;
    float acc[32];
#pragma unroll
    for (int i = 0; i < 32; ++i) acc[i] = 0.f;

    for (int cI = 0; cI < nc; ++cI) {
        const float sc = EXP2(mc[cI] - M);
        L += sc * lc[cI];
        const unsigned short* op = Opart + (size_t)slots[cI] * (128 * 64) + row * 64 + ds;
#pragma unroll
        for (int g = 0; g < 4; ++g) {
            const ushortx8 a = *(const ushortx8*)(op + g * 8);
#pragma unroll
            for (int i = 0; i < 8; ++i) acc[g * 8 + i] += sc * bf2f(a[i]);
        }
    }
    const float inv = 1.0f / L;
    unsigned short* dst = AO + (size_t)(qb * 128 + row) * DMODEL + h * 64 + ds;
#pragma unroll
    for (int g = 0; g < 4; ++g) {
        ushortx8 ov;
#pragma unroll
        for (int i = 0; i < 8; ++i) ov[i] = f2bf(acc[g * 8 + i] * inv);
        *(ushortx8*)(dst + g * 8) = ov;
    }
}

extern "C" void kernel_launch(void* const* d_in, const int* in_sizes, int n_in,
                              void* d_out, int out_size, void* d_ws, size_t ws_size,
                              hipStream_t stream) {
    const float* x  = (const float*)d_in[0];
    const float* Wq = (const float*)d_in[1];
    const float* Wk = (const float*)d_in[2];
    const float* Wv = (const float*)d_in[3];
    const float* Wo = (const float*)d_in[4];

    const int xElems = S_LEN * DMODEL;
    const int wElems = DMODEL * DMODEL;
    const size_t headElems = (size_t)NHEADS * S_LEN * 64;
    const int nslots = NHEADS * WPH;   // 1728

    unsigned short* xb  = (unsigned short*)d_ws;
    unsigned short* Wqb = xb  + xElems;
    unsigned short* Wkb = Wqb + wElems;
    unsigned short* Wvb = Wkb + wElems;
    unsigned short* Wob = Wvb + wElems;
    unsigned short* Qh  = Wob + wElems;
    unsigned short* Kh  = Qh + headElems;
    unsigned short* Vt  = Kh + headElems;                    // [H][64][S]
    unsigned short* AO  = Vt + headElems;
    unsigned short* Opart = AO + xElems;                     // [1728][128*64]
    float* ml = (float*)(Opart + (size_t)nslots * 128 * 64); // [1728][256]

    cvt_all<<<dim3(2688), dim3(256), 0, stream>>>(x, Wq, Wk, Wv, Wo,
                                                  xb, Wqb, Wkb, Wvb, Wob);

    gemm_nt<1><<<dim3(DMODEL / 128, S_LEN / 64, 3), dim3(256), 0, stream>>>(
        xb, Wqb, Wkb, Wvb, Qh, Kh, Vt, nullptr, S_LEN, DMODEL, DMODEL);

    flash_part<<<dim3(WPH, NHEADS), dim3(256), 0, stream>>>(Qh, Kh, Vt, AO, Opart, ml);

    combine<<<dim3(28, NHEADS), dim3(256), 0, stream>>>(Opart, ml, AO);

    gemm_nt<0><<<dim3(DMODEL / 128, S_LEN / 64, 1), dim3(256), 0, stream>>>(
        AO, Wob, nullptr, nullptr, nullptr, nullptr, nullptr,
        (float*)d_out, S_LEN, DMODEL, DMODEL);
}